// Round 1
// baseline (1785.539 us; speedup 1.0000x reference)
//
#include <hip/hip_runtime.h>

#define DEV __device__ __forceinline__
DEV float relu_(float x) { return fmaxf(x, 0.0f); }

DEV void knn_insert(float (&bd)[5], int (&bi)[5], float d, int j) {
  if (d >= bd[4]) return;
  bd[4] = d; bi[4] = j;
#pragma unroll
  for (int p = 4; p > 0; --p) {
    if (bd[p] < bd[p - 1]) {
      float td = bd[p]; bd[p] = bd[p - 1]; bd[p - 1] = td;
      int ti = bi[p]; bi[p] = bi[p - 1]; bi[p - 1] = ti;
    }
  }
}

// ---------------- Kernel 1: kNN on pos (F=3) ----------------
// grid 256 (32 batches x 8 query chunks), block 256
__global__ __launch_bounds__(256) void k_knn1(const float* __restrict__ pos,
                                              int* __restrict__ idx1) {
  __shared__ float ps[2048 * 3];
  __shared__ float sq[2048];
  int tid = threadIdx.x;
  int b = blockIdx.x >> 3, ch = blockIdx.x & 7;
  const float* src = pos + b * 2048 * 3;
  for (int u = tid; u < 6144; u += 256) ps[u] = src[u];
  __syncthreads();
  for (int u = tid; u < 2048; u += 256) {
    float x = ps[u * 3], y = ps[u * 3 + 1], z = ps[u * 3 + 2];
    sq[u] = fmaf(z, z, fmaf(y, y, x * x));
  }
  __syncthreads();
  int i = ch * 256 + tid;
  float qx = ps[i * 3], qy = ps[i * 3 + 1], qz = ps[i * 3 + 2];
  float qsq = sq[i];
  float bd[5] = {1e30f, 1e30f, 1e30f, 1e30f, 1e30f};
  int bi[5] = {0, 0, 0, 0, 0};
  for (int j = 0; j < 2048; ++j) {
    float px = ps[j * 3], py = ps[j * 3 + 1], pz = ps[j * 3 + 2];
    float dot = fmaf(qz, pz, fmaf(qy, py, qx * px));
    float d = (qsq + sq[j]) - 2.0f * dot;
    knn_insert(bd, bi, d, j);
  }
  int* op = idx1 + (b * 2048 + i) * 5;
#pragma unroll
  for (int k = 0; k < 5; ++k) op[k] = bi[k];
}

// ---------------- Kernel 2: EdgeConv1 (6->64->64->64, max over 5) ----------------
// grid 4096 (16 points/block), block 256 = 64 channels x 4 point-groups
__global__ __launch_bounds__(256) void k_edge1(
    const float* __restrict__ pos, const int* __restrict__ idx1,
    const float* __restrict__ w1a, const float* __restrict__ b1a,
    const float* __restrict__ s1a, const float* __restrict__ h1a,
    const float* __restrict__ w1b, const float* __restrict__ b1b,
    const float* __restrict__ s1b, const float* __restrict__ h1b,
    const float* __restrict__ w1c, const float* __restrict__ b1c,
    const float* __restrict__ s1c, const float* __restrict__ h1c,
    float* __restrict__ x1) {
  __shared__ float wA[384], wB[4096], wC[4096];
  __shared__ float cA[192], cB[192], cC[192];
  __shared__ float hb1[1024], hb2[1024];
  int tid = threadIdx.x;
  for (int u = tid; u < 384; u += 256) wA[u] = w1a[u];
  for (int u = tid; u < 4096; u += 256) { wB[u] = w1b[u]; wC[u] = w1c[u]; }
  if (tid < 64) {
    cA[tid] = b1a[tid]; cA[64 + tid] = s1a[tid]; cA[128 + tid] = h1a[tid];
    cB[tid] = b1b[tid]; cB[64 + tid] = s1b[tid]; cB[128 + tid] = h1b[tid];
    cC[tid] = b1c[tid]; cC[64 + tid] = s1c[tid]; cC[128 + tid] = h1c[tid];
  }
  __syncthreads();
  int c = tid & 63, pg = tid >> 6;
  int n0 = blockIdx.x * 16;
  int b = n0 >> 11;
  int nn[4];
  float xi[4][3];
#pragma unroll
  for (int pp = 0; pp < 4; ++pp) {
    nn[pp] = n0 + pg * 4 + pp;
    xi[pp][0] = pos[nn[pp] * 3];
    xi[pp][1] = pos[nn[pp] * 3 + 1];
    xi[pp][2] = pos[nn[pp] * 3 + 2];
  }
  float am[4] = {-3.4e38f, -3.4e38f, -3.4e38f, -3.4e38f};
  for (int k = 0; k < 5; ++k) {
#pragma unroll
    for (int pp = 0; pp < 4; ++pp) {
      int j = idx1[nn[pp] * 5 + k];
      int jr = (b << 11) + j;
      float e3 = pos[jr * 3] - xi[pp][0];
      float e4 = pos[jr * 3 + 1] - xi[pp][1];
      float e5 = pos[jr * 3 + 2] - xi[pp][2];
      float a = xi[pp][0] * wA[c];
      a = fmaf(xi[pp][1], wA[64 + c], a);
      a = fmaf(xi[pp][2], wA[128 + c], a);
      a = fmaf(e3, wA[192 + c], a);
      a = fmaf(e4, wA[256 + c], a);
      a = fmaf(e5, wA[320 + c], a);
      hb1[(pg * 4 + pp) * 64 + c] = relu_(a + cA[c]) * cA[64 + c] + cA[128 + c];
    }
    __syncthreads();
    {
      float a2[4] = {0, 0, 0, 0};
      for (int f = 0; f < 64; ++f) {
        float wv = wB[f * 64 + c];
#pragma unroll
        for (int pp = 0; pp < 4; ++pp)
          a2[pp] = fmaf(hb1[(pg * 4 + pp) * 64 + f], wv, a2[pp]);
      }
#pragma unroll
      for (int pp = 0; pp < 4; ++pp)
        hb2[(pg * 4 + pp) * 64 + c] = relu_(a2[pp] + cB[c]) * cB[64 + c] + cB[128 + c];
    }
    __syncthreads();
    {
      float a3[4] = {0, 0, 0, 0};
      for (int f = 0; f < 64; ++f) {
        float wv = wC[f * 64 + c];
#pragma unroll
        for (int pp = 0; pp < 4; ++pp)
          a3[pp] = fmaf(hb2[(pg * 4 + pp) * 64 + f], wv, a3[pp]);
      }
#pragma unroll
      for (int pp = 0; pp < 4; ++pp)
        am[pp] = fmaxf(am[pp], relu_(a3[pp] + cC[c]) * cC[64 + c] + cC[128 + c]);
    }
    __syncthreads();
  }
#pragma unroll
  for (int pp = 0; pp < 4; ++pp) x1[nn[pp] * 64 + c] = am[pp];
}

// ---------------- Kernel 3: kNN on x1 (F=64) ----------------
// grid 256 (32 batches x 8 query chunks), block 256 (1 query/thread)
__global__ __launch_bounds__(256) void k_knn2(const float* __restrict__ x1,
                                              int* __restrict__ idx2) {
  __shared__ __align__(16) float cand[8192];
  __shared__ float csq[128];
  int tid = threadIdx.x;
  int b = blockIdx.x >> 3, ch = blockIdx.x & 7;
  int i = ch * 256 + tid;
  const float* qr = x1 + (b * 2048 + i) * 64;
  float q[64];
#pragma unroll
  for (int f = 0; f < 64; f += 4) {
    float4 g = *(const float4*)(qr + f);
    q[f] = g.x; q[f + 1] = g.y; q[f + 2] = g.z; q[f + 3] = g.w;
  }
  float s0 = 0, s1 = 0, s2 = 0, s3 = 0;
#pragma unroll
  for (int f = 0; f < 64; f += 4) {
    s0 = fmaf(q[f], q[f], s0);
    s1 = fmaf(q[f + 1], q[f + 1], s1);
    s2 = fmaf(q[f + 2], q[f + 2], s2);
    s3 = fmaf(q[f + 3], q[f + 3], s3);
  }
  float qsq = (s0 + s1) + (s2 + s3);
  float bd[5] = {1e30f, 1e30f, 1e30f, 1e30f, 1e30f};
  int bi[5] = {0, 0, 0, 0, 0};
  for (int t = 0; t < 16; ++t) {
    __syncthreads();  // previous tile consumers done
    const float* src = x1 + (b * 2048 + t * 128) * 64;
    for (int u = tid * 4; u < 8192; u += 1024)
      *(float4*)(cand + u) = *(const float4*)(src + u);
    __syncthreads();
    if (tid < 128) {
      const float* cf = cand + tid * 64;
      float t0 = 0, t1 = 0, t2 = 0, t3 = 0;
#pragma unroll
      for (int f = 0; f < 64; f += 4) {
        t0 = fmaf(cf[f], cf[f], t0);
        t1 = fmaf(cf[f + 1], cf[f + 1], t1);
        t2 = fmaf(cf[f + 2], cf[f + 2], t2);
        t3 = fmaf(cf[f + 3], cf[f + 3], t3);
      }
      csq[tid] = (t0 + t1) + (t2 + t3);
    }
    __syncthreads();
    for (int cc = 0; cc < 128; ++cc) {
      const float* cf = cand + cc * 64;
      float d0 = 0, d1 = 0, d2 = 0, d3 = 0;
#pragma unroll
      for (int f = 0; f < 64; f += 4) {
        d0 = fmaf(q[f], cf[f], d0);
        d1 = fmaf(q[f + 1], cf[f + 1], d1);
        d2 = fmaf(q[f + 2], cf[f + 2], d2);
        d3 = fmaf(q[f + 3], cf[f + 3], d3);
      }
      float dot = (d0 + d1) + (d2 + d3);
      float d = (qsq + csq[cc]) - 2.0f * dot;
      knn_insert(bd, bi, d, t * 128 + cc);
    }
  }
  int* op = idx2 + (b * 2048 + i) * 5;
#pragma unroll
  for (int k = 0; k < 5; ++k) op[k] = bi[k];
}

// ---------------- Kernel 4a: P = x1@(W1-W2), Q = x1@W2 ----------------
// EdgeConv2 decomposition. grid 4096 (1024 point-tiles x 4 out-chunks), block 256
__global__ __launch_bounds__(256) void k_pq(const float* __restrict__ x1,
                                            const float* __restrict__ w2,
                                            float* __restrict__ P,
                                            float* __restrict__ Q) {
  __shared__ __align__(16) float ins[4096];  // [k(64)][p(64)]
  int tid = threadIdx.x;
  int pt = blockIdx.x >> 2, oc = blockIdx.x & 3;
  int n0 = pt * 64;
  {
    int p = tid & 63, kq = tid >> 6;
#pragma unroll
    for (int u = 0; u < 4; ++u) {
      int k = kq * 16 + u * 4;
      float4 g = *(const float4*)(x1 + (n0 + p) * 64 + k);
      ins[(k + 0) * 64 + p] = g.x;
      ins[(k + 1) * 64 + p] = g.y;
      ins[(k + 2) * 64 + p] = g.z;
      ins[(k + 3) * 64 + p] = g.w;
    }
  }
  __syncthreads();
  int cg = tid >> 4, pg = tid & 15;
  int vcol = oc * 64 + cg * 4;
  bool isP = (oc < 2);
  int col = isP ? vcol : (vcol - 128);
  float acc[4][4] = {{0, 0, 0, 0}, {0, 0, 0, 0}, {0, 0, 0, 0}, {0, 0, 0, 0}};
#pragma unroll 4
  for (int k = 0; k < 64; ++k) {
    float4 av = *(const float4*)(ins + k * 64 + pg * 4);
    float a[4] = {av.x, av.y, av.z, av.w};
    float4 wBv = *(const float4*)(w2 + (64 + k) * 128 + col);  // W2 rows
    float wv[4];
    if (isP) {
      float4 wAv = *(const float4*)(w2 + k * 128 + col);
      wv[0] = wAv.x - wBv.x; wv[1] = wAv.y - wBv.y;
      wv[2] = wAv.z - wBv.z; wv[3] = wAv.w - wBv.w;
    } else {
      wv[0] = wBv.x; wv[1] = wBv.y; wv[2] = wBv.z; wv[3] = wBv.w;
    }
#pragma unroll
    for (int ii = 0; ii < 4; ++ii)
#pragma unroll
      for (int jj = 0; jj < 4; ++jj)
        acc[ii][jj] = fmaf(a[ii], wv[jj], acc[ii][jj]);
  }
  float* base = (isP ? P : Q);
#pragma unroll
  for (int ii = 0; ii < 4; ++ii) {
    int n = n0 + pg * 4 + ii;
    float4 o = {acc[ii][0], acc[ii][1], acc[ii][2], acc[ii][3]};
    *(float4*)(base + n * 128 + col) = o;
  }
}

// ---------------- Kernel 4b: gather-max + activation (x2) ----------------
// PX holds P on entry, final x2 on exit (element-wise in-place safe).
// grid 32768 (2 points/block), block 256
__global__ __launch_bounds__(256) void k_gmax(float* __restrict__ PX,
                                              const float* __restrict__ Q,
                                              const int* __restrict__ idx2,
                                              const float* __restrict__ b2,
                                              const float* __restrict__ s2,
                                              const float* __restrict__ h2v) {
  int tid = threadIdx.x;
  int c = tid & 127, p = tid >> 7;
  int n = blockIdx.x * 2 + p;  // global point 0..65535
  int b = n >> 11;
  const int* ip = idx2 + n * 5;
  float m = -3.4e38f;
#pragma unroll
  for (int k = 0; k < 5; ++k) {
    int j = ip[k];
    m = fmaxf(m, Q[(b * 2048 + j) * 128 + c]);
  }
  float v = PX[n * 128 + c] + m + b2[c];
  PX[n * 128 + c] = relu_(v) * s2[c] + h2v[c];
}

// ---------------- Kernel 5: Linear 192->1024 fused with max-pool ----------------
// grid 1024 = 32 b x 16 ch-chunks(64) x 2 point-splits; block 256 = 16cg x 16pg, 4x4 tile
__global__ __launch_bounds__(256) void k_linl(const float* __restrict__ x1,
                                              const float* __restrict__ x2,
                                              const float* __restrict__ wl,
                                              const float* __restrict__ bl,
                                              const float* __restrict__ sl,
                                              const float* __restrict__ hl,
                                              float* __restrict__ pool) {
  __shared__ __align__(16) float ins[192 * 64];  // [k][p]
  __shared__ float red[64 * 16];
  int tid = threadIdx.x;
  int blk = blockIdx.x;
  int b = blk >> 5, cch = (blk >> 1) & 15, sp = blk & 1;
  int cg = tid >> 4, pg = tid & 15;
  int cbase = cch * 64 + cg * 4;
  int pload = tid & 63, fq = tid >> 6;
  float chmax[4] = {-3.4e38f, -3.4e38f, -3.4e38f, -3.4e38f};
  for (int tl = 0; tl < 16; ++tl) {
    int n0 = sp * 1024 + tl * 64;
    int row = b * 2048 + n0 + pload;
#pragma unroll
    for (int u = 0; u < 12; ++u) {
      int f = fq * 48 + u * 4;
      const float* src = (f < 64) ? (x1 + row * 64 + f) : (x2 + row * 128 + (f - 64));
      float4 g = *(const float4*)src;
      ins[(f + 0) * 64 + pload] = g.x;
      ins[(f + 1) * 64 + pload] = g.y;
      ins[(f + 2) * 64 + pload] = g.z;
      ins[(f + 3) * 64 + pload] = g.w;
    }
    __syncthreads();
    float acc[4][4] = {{0, 0, 0, 0}, {0, 0, 0, 0}, {0, 0, 0, 0}, {0, 0, 0, 0}};
#pragma unroll 4
    for (int k = 0; k < 192; ++k) {
      float4 av = *(const float4*)(ins + k * 64 + pg * 4);
      float a[4] = {av.x, av.y, av.z, av.w};
      float4 wv4 = *(const float4*)(wl + k * 1024 + cbase);
      float w[4] = {wv4.x, wv4.y, wv4.z, wv4.w};
#pragma unroll
      for (int ii = 0; ii < 4; ++ii)
#pragma unroll
        for (int jj = 0; jj < 4; ++jj)
          acc[ii][jj] = fmaf(a[ii], w[jj], acc[ii][jj]);
    }
#pragma unroll
    for (int jj = 0; jj < 4; ++jj)
#pragma unroll
      for (int ii = 0; ii < 4; ++ii)
        chmax[jj] = fmaxf(chmax[jj], acc[ii][jj]);
    __syncthreads();
  }
#pragma unroll
  for (int jj = 0; jj < 4; ++jj) red[(cg * 4 + jj) * 16 + pg] = chmax[jj];
  __syncthreads();
  if (tid < 64) {
    float m = red[tid * 16];
#pragma unroll
    for (int p2 = 1; p2 < 16; ++p2) m = fmaxf(m, red[tid * 16 + p2]);
    int c = cch * 64 + tid;
    // relu*s+h is monotone (s>0): apply once after max over points
    pool[(b * 2 + sp) * 1024 + c] = relu_(m + bl[c]) * sl[c] + hl[c];
  }
}

// ---------------- Kernel 6: head MLP ----------------
// grid 32 (1 block/batch), block 256
__global__ __launch_bounds__(256) void k_head(
    const float* __restrict__ pool, const float* __restrict__ wm1,
    const float* __restrict__ bm1, const float* __restrict__ sm1,
    const float* __restrict__ hm1, const float* __restrict__ wm2,
    const float* __restrict__ bm2, const float* __restrict__ sm2,
    const float* __restrict__ hm2, const float* __restrict__ wout,
    const float* __restrict__ bout, float* __restrict__ out) {
  __shared__ float p_s[1024], h1_s[512], h2_s[256];
  int b = blockIdx.x, tid = threadIdx.x;
  for (int c = tid; c < 1024; c += 256)
    p_s[c] = fmaxf(pool[(b * 2) * 1024 + c], pool[(b * 2 + 1) * 1024 + c]);
  __syncthreads();
  for (int c = tid; c < 512; c += 256) {
    float a = 0;
#pragma unroll 4
    for (int f = 0; f < 1024; ++f) a = fmaf(p_s[f], wm1[f * 512 + c], a);
    h1_s[c] = relu_(a + bm1[c]) * sm1[c] + hm1[c];
  }
  __syncthreads();
  if (tid < 256) {
    float a = 0;
#pragma unroll 4
    for (int f = 0; f < 512; ++f) a = fmaf(h1_s[f], wm2[f * 256 + tid], a);
    h2_s[tid] = relu_(a + bm2[tid]) * sm2[tid] + hm2[tid];
  }
  __syncthreads();
  if (tid < 2) {
    float a = 0;
#pragma unroll 4
    for (int f = 0; f < 256; ++f) a = fmaf(h2_s[f], wout[f * 2 + tid], a);
    out[b * 2 + tid] = a + bout[tid];
  }
}

extern "C" void kernel_launch(void* const* d_in, const int* in_sizes, int n_in,
                              void* d_out, int out_size, void* d_ws, size_t ws_size,
                              hipStream_t stream) {
  const float* pos = (const float*)d_in[0];
  const float* w1a = (const float*)d_in[1];
  const float* b1a = (const float*)d_in[2];
  const float* s1a = (const float*)d_in[3];
  const float* h1a = (const float*)d_in[4];
  const float* w1b = (const float*)d_in[5];
  const float* b1b = (const float*)d_in[6];
  const float* s1b = (const float*)d_in[7];
  const float* h1b = (const float*)d_in[8];
  const float* w1c = (const float*)d_in[9];
  const float* b1c = (const float*)d_in[10];
  const float* s1c = (const float*)d_in[11];
  const float* h1c = (const float*)d_in[12];
  const float* w2 = (const float*)d_in[13];
  const float* b2 = (const float*)d_in[14];
  const float* s2 = (const float*)d_in[15];
  const float* h2 = (const float*)d_in[16];
  const float* wl = (const float*)d_in[17];
  const float* bl = (const float*)d_in[18];
  const float* sl = (const float*)d_in[19];
  const float* hl = (const float*)d_in[20];
  const float* wm1 = (const float*)d_in[21];
  const float* bm1 = (const float*)d_in[22];
  const float* sm1 = (const float*)d_in[23];
  const float* hm1 = (const float*)d_in[24];
  const float* wm2 = (const float*)d_in[25];
  const float* bm2 = (const float*)d_in[26];
  const float* sm2 = (const float*)d_in[27];
  const float* hm2 = (const float*)d_in[28];
  const float* wout = (const float*)d_in[29];
  const float* bout = (const float*)d_in[30];
  float* out = (float*)d_out;

  // workspace layout (floats): x1 | x2(=P) | Q | pool | idx (reused for knn1/knn2)
  float* x1 = (float*)d_ws;                 // 32*2048*64   = 4,194,304
  float* x2 = x1 + 4194304;                 // 32*2048*128  = 8,388,608 (P aliased)
  float* Q = x2 + 8388608;                  // 8,388,608
  float* pool = Q + 8388608;                // 32*2*1024    = 65,536
  int* idx = (int*)(pool + 65536);          // 32*2048*5    = 327,680

  k_knn1<<<256, 256, 0, stream>>>(pos, idx);
  k_edge1<<<4096, 256, 0, stream>>>(pos, idx, w1a, b1a, s1a, h1a, w1b, b1b, s1b,
                                    h1b, w1c, b1c, s1c, h1c, x1);
  k_knn2<<<256, 256, 0, stream>>>(x1, idx);
  k_pq<<<4096, 256, 0, stream>>>(x1, w2, x2 /*P*/, Q);
  k_gmax<<<32768, 256, 0, stream>>>(x2 /*P in, x2 out*/, Q, idx, b2, s2, h2);
  k_linl<<<1024, 256, 0, stream>>>(x1, x2, wl, bl, sl, hl, pool);
  k_head<<<32, 256, 0, stream>>>(pool, wm1, bm1, sm1, hm1, wm2, bm2, sm2, hm2,
                                 wout, bout, out);
}

// Round 2
// 1426.706 us; speedup vs baseline: 1.2515x; 1.2515x over previous
//
#include <hip/hip_runtime.h>

#define DEV __device__ __forceinline__
DEV float relu_(float x) { return fmaxf(x, 0.0f); }

DEV void knn_insert(float (&bd)[5], int (&bi)[5], float d, int j) {
  if (d >= bd[4]) return;
  bd[4] = d; bi[4] = j;
#pragma unroll
  for (int p = 4; p > 0; --p) {
    if (bd[p] < bd[p - 1]) {
      float td = bd[p]; bd[p] = bd[p - 1]; bd[p - 1] = td;
      int ti = bi[p]; bi[p] = bi[p - 1]; bi[p - 1] = ti;
    }
  }
}

// ---------------- Kernel 1: kNN on pos (F=3), 4-way candidate split ----------------
// grid 1024 (32 b x 32 query-chunks of 64), block 256 = 64 queries x 4 cand-subranges
__global__ __launch_bounds__(256) void k_knn1(const float* __restrict__ pos,
                                              int* __restrict__ idx1) {
  __shared__ float ps[6144];
  __shared__ float sqs[2048];
  __shared__ float md[640];
  __shared__ int mi[640];
  int tid = threadIdx.x;
  int b = blockIdx.x >> 5, qc = blockIdx.x & 31;
  const float* src = pos + b * 6144;
  for (int u = tid; u < 6144; u += 256) ps[u] = src[u];
  __syncthreads();
  for (int u = tid; u < 2048; u += 256) {
    float x = ps[u * 3], y = ps[u * 3 + 1], z = ps[u * 3 + 2];
    sqs[u] = fmaf(z, z, fmaf(y, y, x * x));
  }
  __syncthreads();
  int q = tid & 63, sub = tid >> 6;  // sub is wave-uniform
  int qi = qc * 64 + q;
  float qx = ps[qi * 3], qy = ps[qi * 3 + 1], qz = ps[qi * 3 + 2];
  float qsq = sqs[qi];
  float bd[5] = {1e30f, 1e30f, 1e30f, 1e30f, 1e30f};
  int bi[5] = {0, 0, 0, 0, 0};
  int j0 = sub * 512;
  for (int j = j0; j < j0 + 512; ++j) {
    float px = ps[j * 3], py = ps[j * 3 + 1], pz = ps[j * 3 + 2];
    float dot = fmaf(qz, pz, fmaf(qy, py, qx * px));
    float d = (qsq + sqs[j]) - 2.0f * dot;
    knn_insert(bd, bi, d, j);
  }
  // tree-merge 4 partial lists -> 1
  for (int half = 2; half >= 1; half >>= 1) {
    __syncthreads();
    if (sub >= half && sub < 2 * half) {
      int slot = (q * 2 + (sub - half)) * 5;
#pragma unroll
      for (int k = 0; k < 5; ++k) { md[slot + k] = bd[k]; mi[slot + k] = bi[k]; }
    }
    __syncthreads();
    if (sub < half) {
      int slot = (q * 2 + sub) * 5;
#pragma unroll
      for (int k = 0; k < 5; ++k) knn_insert(bd, bi, md[slot + k], mi[slot + k]);
    }
  }
  if (sub == 0) {
    int* op = idx1 + (b * 2048 + qi) * 5;
#pragma unroll
    for (int k = 0; k < 5; ++k) op[k] = bi[k];
  }
}

// ---------------- Kernel 2: EdgeConv1 -> writes x1 TRANSPOSED [b][f][n] + sq ----------------
// grid 4096 (16 points/block), block 256 = 64 channels x 4 point-groups
__global__ __launch_bounds__(256) void k_edge1(
    const float* __restrict__ pos, const int* __restrict__ idx1,
    const float* __restrict__ w1a, const float* __restrict__ b1a,
    const float* __restrict__ s1a, const float* __restrict__ h1a,
    const float* __restrict__ w1b, const float* __restrict__ b1b,
    const float* __restrict__ s1b, const float* __restrict__ h1b,
    const float* __restrict__ w1c, const float* __restrict__ b1c,
    const float* __restrict__ s1c, const float* __restrict__ h1c,
    float* __restrict__ x1t, float* __restrict__ sqo) {
  __shared__ float wA[384], wB[4096], wC[4096];
  __shared__ float cA[192], cB[192], cC[192];
  __shared__ float hb1[1024], hb2[1024];
  int tid = threadIdx.x;
  for (int u = tid; u < 384; u += 256) wA[u] = w1a[u];
  for (int u = tid; u < 4096; u += 256) { wB[u] = w1b[u]; wC[u] = w1c[u]; }
  if (tid < 64) {
    cA[tid] = b1a[tid]; cA[64 + tid] = s1a[tid]; cA[128 + tid] = h1a[tid];
    cB[tid] = b1b[tid]; cB[64 + tid] = s1b[tid]; cB[128 + tid] = h1b[tid];
    cC[tid] = b1c[tid]; cC[64 + tid] = s1c[tid]; cC[128 + tid] = h1c[tid];
  }
  __syncthreads();
  int c = tid & 63, pg = tid >> 6;  // c = lane id (wave-aligned), pg = wave id
  int n0 = blockIdx.x * 16;
  int b = n0 >> 11;
  int nn[4];
  float xi[4][3];
#pragma unroll
  for (int pp = 0; pp < 4; ++pp) {
    nn[pp] = n0 + pg * 4 + pp;
    xi[pp][0] = pos[nn[pp] * 3];
    xi[pp][1] = pos[nn[pp] * 3 + 1];
    xi[pp][2] = pos[nn[pp] * 3 + 2];
  }
  float am[4] = {-3.4e38f, -3.4e38f, -3.4e38f, -3.4e38f};
  for (int k = 0; k < 5; ++k) {
#pragma unroll
    for (int pp = 0; pp < 4; ++pp) {
      int j = idx1[nn[pp] * 5 + k];
      int jr = (b << 11) + j;
      float e3 = pos[jr * 3] - xi[pp][0];
      float e4 = pos[jr * 3 + 1] - xi[pp][1];
      float e5 = pos[jr * 3 + 2] - xi[pp][2];
      float a = xi[pp][0] * wA[c];
      a = fmaf(xi[pp][1], wA[64 + c], a);
      a = fmaf(xi[pp][2], wA[128 + c], a);
      a = fmaf(e3, wA[192 + c], a);
      a = fmaf(e4, wA[256 + c], a);
      a = fmaf(e5, wA[320 + c], a);
      hb1[(pg * 4 + pp) * 64 + c] = relu_(a + cA[c]) * cA[64 + c] + cA[128 + c];
    }
    __syncthreads();
    {
      float a2[4] = {0, 0, 0, 0};
      for (int f = 0; f < 64; ++f) {
        float wv = wB[f * 64 + c];
#pragma unroll
        for (int pp = 0; pp < 4; ++pp)
          a2[pp] = fmaf(hb1[(pg * 4 + pp) * 64 + f], wv, a2[pp]);
      }
#pragma unroll
      for (int pp = 0; pp < 4; ++pp)
        hb2[(pg * 4 + pp) * 64 + c] = relu_(a2[pp] + cB[c]) * cB[64 + c] + cB[128 + c];
    }
    __syncthreads();
    {
      float a3[4] = {0, 0, 0, 0};
      for (int f = 0; f < 64; ++f) {
        float wv = wC[f * 64 + c];
#pragma unroll
        for (int pp = 0; pp < 4; ++pp)
          a3[pp] = fmaf(hb2[(pg * 4 + pp) * 64 + f], wv, a3[pp]);
      }
#pragma unroll
      for (int pp = 0; pp < 4; ++pp)
        am[pp] = fmaxf(am[pp], relu_(a3[pp] + cC[c]) * cC[64 + c] + cC[128 + c]);
    }
    __syncthreads();
  }
  // transposed write + wave shuffle-reduced row norms
#pragma unroll
  for (int pp = 0; pp < 4; ++pp) {
    float v = am[pp];
    int nloc = nn[pp] & 2047;
    x1t[(b * 64 + c) * 2048 + nloc] = v;
    float s = v * v;
    s += __shfl_xor(s, 1);
    s += __shfl_xor(s, 2);
    s += __shfl_xor(s, 4);
    s += __shfl_xor(s, 8);
    s += __shfl_xor(s, 16);
    s += __shfl_xor(s, 32);
    if (c == 0) sqo[nn[pp]] = s;
  }
}

// ---------------- Kernel 3: kNN on x1 (F=64), GEMM-tiled ----------------
// grid 1024 (32 b x 32 query-chunks of 64), block 256 = 16 cg x 16 pg, 4x4 tile
__global__ __launch_bounds__(256) void k_knn2(const float* __restrict__ x1t,
                                              const float* __restrict__ sq,
                                              int* __restrict__ idx2) {
  __shared__ __align__(16) float smem[8192];  // As[64f][64q] | Bs[64f][64c]
  __shared__ float csq_s[64];
  float* As = smem;
  float* Bs = smem + 4096;
  float* md = smem;               // merge overlay (after tiles)
  int* mi = (int*)(smem + 2560);
  int tid = threadIdx.x;
  int b = blockIdx.x >> 5, qc = blockIdx.x & 31;
  int q0 = qc * 64;
  int pg = tid & 15, cg = tid >> 4;
  // load A tile (queries) once, coalesced from transposed x1
  {
    int fr = tid >> 4, c4 = tid & 15;
#pragma unroll
    for (int it = 0; it < 4; ++it) {
      int f = fr + it * 16;
      float4 g = *(const float4*)(x1t + (b * 64 + f) * 2048 + q0 + c4 * 4);
      *(float4*)(As + f * 64 + c4 * 4) = g;
    }
  }
  float qs[4];
#pragma unroll
  for (int ii = 0; ii < 4; ++ii) qs[ii] = sq[b * 2048 + q0 + pg * 4 + ii];
  float bd[4][5];
  int bi[4][5];
#pragma unroll
  for (int ii = 0; ii < 4; ++ii)
#pragma unroll
    for (int k = 0; k < 5; ++k) { bd[ii][k] = 1e30f; bi[ii][k] = 0; }
  for (int t = 0; t < 32; ++t) {
    __syncthreads();  // prev tile consumers done (also covers A-load on t=0)
    {
      int fr = tid >> 4, c4 = tid & 15;
#pragma unroll
      for (int it = 0; it < 4; ++it) {
        int f = fr + it * 16;
        float4 g = *(const float4*)(x1t + (b * 64 + f) * 2048 + t * 64 + c4 * 4);
        *(float4*)(Bs + f * 64 + c4 * 4) = g;
      }
      if (tid < 16)
        *(float4*)(csq_s + tid * 4) = *(const float4*)(sq + b * 2048 + t * 64 + tid * 4);
    }
    __syncthreads();
    float acc[4][4] = {{0, 0, 0, 0}, {0, 0, 0, 0}, {0, 0, 0, 0}, {0, 0, 0, 0}};
#pragma unroll 4
    for (int k = 0; k < 64; ++k) {
      float4 a4 = *(const float4*)(As + k * 64 + pg * 4);
      float4 b4 = *(const float4*)(Bs + k * 64 + cg * 4);
      float av[4] = {a4.x, a4.y, a4.z, a4.w};
      float bv[4] = {b4.x, b4.y, b4.z, b4.w};
#pragma unroll
      for (int ii = 0; ii < 4; ++ii)
#pragma unroll
        for (int jj = 0; jj < 4; ++jj)
          acc[ii][jj] = fmaf(av[ii], bv[jj], acc[ii][jj]);
    }
#pragma unroll
    for (int jj = 0; jj < 4; ++jj) {
      float cj = csq_s[cg * 4 + jj];
      int cid = t * 64 + cg * 4 + jj;
#pragma unroll
      for (int ii = 0; ii < 4; ++ii) {
        float d = (qs[ii] + cj) - 2.0f * acc[ii][jj];
        knn_insert(bd[ii], bi[ii], d, cid);
      }
    }
  }
  // tree-merge 16 cg partial lists -> 1 (LDS overlays A/B region)
  for (int half = 8; half >= 1; half >>= 1) {
    __syncthreads();
    if (cg >= half && cg < 2 * half) {
#pragma unroll
      for (int ii = 0; ii < 4; ++ii) {
        int slot = ((pg * 4 + ii) * 8 + (cg - half)) * 5;
#pragma unroll
        for (int k = 0; k < 5; ++k) { md[slot + k] = bd[ii][k]; mi[slot + k] = bi[ii][k]; }
      }
    }
    __syncthreads();
    if (cg < half) {
#pragma unroll
      for (int ii = 0; ii < 4; ++ii) {
        int slot = ((pg * 4 + ii) * 8 + cg) * 5;
#pragma unroll
        for (int k = 0; k < 5; ++k) knn_insert(bd[ii], bi[ii], md[slot + k], mi[slot + k]);
      }
    }
  }
  if (cg == 0) {
#pragma unroll
    for (int ii = 0; ii < 4; ++ii) {
      int* op = idx2 + (b * 2048 + q0 + pg * 4 + ii) * 5;
#pragma unroll
      for (int k = 0; k < 5; ++k) op[k] = bi[ii][k];
    }
  }
}

// ---------------- Kernel 4a: P = x1@(W1-W2), Q = x1@W2 (x1 transposed input) ----------------
// grid 4096 (1024 point-tiles x 4 out-chunks), block 256
__global__ __launch_bounds__(256) void k_pq(const float* __restrict__ x1t,
                                            const float* __restrict__ w2,
                                            float* __restrict__ P,
                                            float* __restrict__ Q) {
  __shared__ __align__(16) float ins[4096];  // [k(64)][p(64)]
  int tid = threadIdx.x;
  int pt = blockIdx.x >> 2, oc = blockIdx.x & 3;
  int n0 = pt * 64;
  int b = n0 >> 11, nloc = n0 & 2047;
  {
    int fr = tid >> 4, c4 = tid & 15;
#pragma unroll
    for (int it = 0; it < 4; ++it) {
      int f = fr + it * 16;
      float4 g = *(const float4*)(x1t + (b * 64 + f) * 2048 + nloc + c4 * 4);
      *(float4*)(ins + f * 64 + c4 * 4) = g;
    }
  }
  __syncthreads();
  int cg = tid >> 4, pg = tid & 15;
  int vcol = oc * 64 + cg * 4;
  bool isP = (oc < 2);
  int col = isP ? vcol : (vcol - 128);
  float acc[4][4] = {{0, 0, 0, 0}, {0, 0, 0, 0}, {0, 0, 0, 0}, {0, 0, 0, 0}};
#pragma unroll 4
  for (int k = 0; k < 64; ++k) {
    float4 av = *(const float4*)(ins + k * 64 + pg * 4);
    float a[4] = {av.x, av.y, av.z, av.w};
    float4 wBv = *(const float4*)(w2 + (64 + k) * 128 + col);  // W2 rows
    float wv[4];
    if (isP) {
      float4 wAv = *(const float4*)(w2 + k * 128 + col);
      wv[0] = wAv.x - wBv.x; wv[1] = wAv.y - wBv.y;
      wv[2] = wAv.z - wBv.z; wv[3] = wAv.w - wBv.w;
    } else {
      wv[0] = wBv.x; wv[1] = wBv.y; wv[2] = wBv.z; wv[3] = wBv.w;
    }
#pragma unroll
    for (int ii = 0; ii < 4; ++ii)
#pragma unroll
      for (int jj = 0; jj < 4; ++jj)
        acc[ii][jj] = fmaf(a[ii], wv[jj], acc[ii][jj]);
  }
  float* base = (isP ? P : Q);
#pragma unroll
  for (int ii = 0; ii < 4; ++ii) {
    int n = n0 + pg * 4 + ii;
    float4 o = {acc[ii][0], acc[ii][1], acc[ii][2], acc[ii][3]};
    *(float4*)(base + n * 128 + col) = o;
  }
}

// ---------------- Kernel 4b: gather-max + activation (x2) ----------------
// grid 32768 (2 points/block), block 256
__global__ __launch_bounds__(256) void k_gmax(float* __restrict__ PX,
                                              const float* __restrict__ Q,
                                              const int* __restrict__ idx2,
                                              const float* __restrict__ b2,
                                              const float* __restrict__ s2,
                                              const float* __restrict__ h2v) {
  int tid = threadIdx.x;
  int c = tid & 127, p = tid >> 7;
  int n = blockIdx.x * 2 + p;
  int b = n >> 11;
  const int* ip = idx2 + n * 5;
  float m = -3.4e38f;
#pragma unroll
  for (int k = 0; k < 5; ++k) {
    int j = ip[k];
    m = fmaxf(m, Q[(b * 2048 + j) * 128 + c]);
  }
  float v = PX[n * 128 + c] + m + b2[c];
  PX[n * 128 + c] = relu_(v) * s2[c] + h2v[c];
}

// ---------------- Kernel 5: Linear 192->1024 fused with max-pool ----------------
// grid 1024 = 32 b x 16 ch-chunks(64) x 2 point-splits; block 256 = 16cg x 16pg, 4x4 tile
__global__ __launch_bounds__(256) void k_linl(const float* __restrict__ x1t,
                                              const float* __restrict__ x2,
                                              const float* __restrict__ wl,
                                              const float* __restrict__ bl,
                                              const float* __restrict__ sl,
                                              const float* __restrict__ hl,
                                              float* __restrict__ pool) {
  __shared__ __align__(16) float ins[192 * 64];  // [k][p]
  __shared__ float red[64 * 16];
  int tid = threadIdx.x;
  int blk = blockIdx.x;
  int b = blk >> 5, cch = (blk >> 1) & 15, sp = blk & 1;
  int cg = tid >> 4, pg = tid & 15;
  int cbase = cch * 64 + cg * 4;
  float chmax[4] = {-3.4e38f, -3.4e38f, -3.4e38f, -3.4e38f};
  for (int tl = 0; tl < 16; ++tl) {
    int n0 = sp * 1024 + tl * 64;
    // f 0..63 straight from transposed x1 (coalesced, conflict-free)
    {
      int fr = tid >> 4, c4 = tid & 15;
#pragma unroll
      for (int it = 0; it < 4; ++it) {
        int f = fr + it * 16;
        float4 g = *(const float4*)(x1t + (b * 64 + f) * 2048 + n0 + c4 * 4);
        *(float4*)(ins + f * 64 + c4 * 4) = g;
      }
    }
    // f 64..191 from x2 rows (in-LDS transpose; scalar stores are 2-way/free)
    {
      int pload = tid & 63, fq = tid >> 6;
      int row = b * 2048 + n0 + pload;
#pragma unroll
      for (int u = 0; u < 8; ++u) {
        int f = 64 + fq * 32 + u * 4;
        float4 g = *(const float4*)(x2 + row * 128 + (f - 64));
        ins[(f + 0) * 64 + pload] = g.x;
        ins[(f + 1) * 64 + pload] = g.y;
        ins[(f + 2) * 64 + pload] = g.z;
        ins[(f + 3) * 64 + pload] = g.w;
      }
    }
    __syncthreads();
    float acc[4][4] = {{0, 0, 0, 0}, {0, 0, 0, 0}, {0, 0, 0, 0}, {0, 0, 0, 0}};
#pragma unroll 4
    for (int k = 0; k < 192; ++k) {
      float4 av = *(const float4*)(ins + k * 64 + pg * 4);
      float a[4] = {av.x, av.y, av.z, av.w};
      float4 wv4 = *(const float4*)(wl + k * 1024 + cbase);
      float w[4] = {wv4.x, wv4.y, wv4.z, wv4.w};
#pragma unroll
      for (int ii = 0; ii < 4; ++ii)
#pragma unroll
        for (int jj = 0; jj < 4; ++jj)
          acc[ii][jj] = fmaf(a[ii], w[jj], acc[ii][jj]);
    }
#pragma unroll
    for (int jj = 0; jj < 4; ++jj)
#pragma unroll
      for (int ii = 0; ii < 4; ++ii)
        chmax[jj] = fmaxf(chmax[jj], acc[ii][jj]);
    __syncthreads();
  }
#pragma unroll
  for (int jj = 0; jj < 4; ++jj) red[(cg * 4 + jj) * 16 + pg] = chmax[jj];
  __syncthreads();
  if (tid < 64) {
    float m = red[tid * 16];
#pragma unroll
    for (int p2 = 1; p2 < 16; ++p2) m = fmaxf(m, red[tid * 16 + p2]);
    int c = cch * 64 + tid;
    pool[(b * 2 + sp) * 1024 + c] = relu_(m + bl[c]) * sl[c] + hl[c];
  }
}

// ---------------- Kernel 6: head MLP ----------------
// grid 32 (1 block/batch), block 256
__global__ __launch_bounds__(256) void k_head(
    const float* __restrict__ pool, const float* __restrict__ wm1,
    const float* __restrict__ bm1, const float* __restrict__ sm1,
    const float* __restrict__ hm1, const float* __restrict__ wm2,
    const float* __restrict__ bm2, const float* __restrict__ sm2,
    const float* __restrict__ hm2, const float* __restrict__ wout,
    const float* __restrict__ bout, float* __restrict__ out) {
  __shared__ float p_s[1024], h1_s[512], h2_s[256];
  int b = blockIdx.x, tid = threadIdx.x;
  for (int c = tid; c < 1024; c += 256)
    p_s[c] = fmaxf(pool[(b * 2) * 1024 + c], pool[(b * 2 + 1) * 1024 + c]);
  __syncthreads();
  for (int c = tid; c < 512; c += 256) {
    float a = 0;
#pragma unroll 4
    for (int f = 0; f < 1024; ++f) a = fmaf(p_s[f], wm1[f * 512 + c], a);
    h1_s[c] = relu_(a + bm1[c]) * sm1[c] + hm1[c];
  }
  __syncthreads();
  if (tid < 256) {
    float a = 0;
#pragma unroll 4
    for (int f = 0; f < 512; ++f) a = fmaf(h1_s[f], wm2[f * 256 + tid], a);
    h2_s[tid] = relu_(a + bm2[tid]) * sm2[tid] + hm2[tid];
  }
  __syncthreads();
  if (tid < 2) {
    float a = 0;
#pragma unroll 4
    for (int f = 0; f < 256; ++f) a = fmaf(h2_s[f], wout[f * 2 + tid], a);
    out[b * 2 + tid] = a + bout[tid];
  }
}

extern "C" void kernel_launch(void* const* d_in, const int* in_sizes, int n_in,
                              void* d_out, int out_size, void* d_ws, size_t ws_size,
                              hipStream_t stream) {
  const float* pos = (const float*)d_in[0];
  const float* w1a = (const float*)d_in[1];
  const float* b1a = (const float*)d_in[2];
  const float* s1a = (const float*)d_in[3];
  const float* h1a = (const float*)d_in[4];
  const float* w1b = (const float*)d_in[5];
  const float* b1b = (const float*)d_in[6];
  const float* s1b = (const float*)d_in[7];
  const float* h1b = (const float*)d_in[8];
  const float* w1c = (const float*)d_in[9];
  const float* b1c = (const float*)d_in[10];
  const float* s1c = (const float*)d_in[11];
  const float* h1c = (const float*)d_in[12];
  const float* w2 = (const float*)d_in[13];
  const float* b2 = (const float*)d_in[14];
  const float* s2 = (const float*)d_in[15];
  const float* h2 = (const float*)d_in[16];
  const float* wl = (const float*)d_in[17];
  const float* bl = (const float*)d_in[18];
  const float* sl = (const float*)d_in[19];
  const float* hl = (const float*)d_in[20];
  const float* wm1 = (const float*)d_in[21];
  const float* bm1 = (const float*)d_in[22];
  const float* sm1 = (const float*)d_in[23];
  const float* hm1 = (const float*)d_in[24];
  const float* wm2 = (const float*)d_in[25];
  const float* bm2 = (const float*)d_in[26];
  const float* sm2 = (const float*)d_in[27];
  const float* hm2 = (const float*)d_in[28];
  const float* wout = (const float*)d_in[29];
  const float* bout = (const float*)d_in[30];
  float* out = (float*)d_out;

  // workspace (floats): x1t | x2(=P) | Q | pool | idx | sq
  float* x1t = (float*)d_ws;            // 32*64*2048  = 4,194,304 (transposed [b][f][n])
  float* x2 = x1t + 4194304;            // 32*2048*128 = 8,388,608 (P aliased)
  float* Q = x2 + 8388608;              // 8,388,608
  float* pool = Q + 8388608;            // 65,536
  int* idx = (int*)(pool + 65536);      // 327,680
  float* sq = (float*)(idx + 327680);   // 65,536

  k_knn1<<<1024, 256, 0, stream>>>(pos, idx);
  k_edge1<<<4096, 256, 0, stream>>>(pos, idx, w1a, b1a, s1a, h1a, w1b, b1b, s1b,
                                    h1b, w1c, b1c, s1c, h1c, x1t, sq);
  k_knn2<<<1024, 256, 0, stream>>>(x1t, sq, idx);
  k_pq<<<4096, 256, 0, stream>>>(x1t, w2, x2 /*P*/, Q);
  k_gmax<<<32768, 256, 0, stream>>>(x2, Q, idx, b2, s2, h2);
  k_linl<<<1024, 256, 0, stream>>>(x1t, x2, wl, bl, sl, hl, pool);
  k_head<<<32, 256, 0, stream>>>(pool, wm1, bm1, sm1, hm1, wm2, bm2, sm2, hm2,
                                 wout, bout, out);
}

// Round 3
// 916.791 us; speedup vs baseline: 1.9476x; 1.5562x over previous
//
#include <hip/hip_runtime.h>

#define DEV __device__ __forceinline__
DEV float relu_(float x) { return fmaxf(x, 0.0f); }

typedef __attribute__((ext_vector_type(4))) float f32x4;
typedef __attribute__((ext_vector_type(8))) __bf16 bf16x8;

DEV void knn_insert(float (&bd)[5], int (&bi)[5], float d, int j) {
  if (d >= bd[4]) return;
  bd[4] = d; bi[4] = j;
#pragma unroll
  for (int p = 4; p > 0; --p) {
    if (bd[p] < bd[p - 1]) {
      float td = bd[p]; bd[p] = bd[p - 1]; bd[p - 1] = td;
      int ti = bi[p]; bi[p] = bi[p - 1]; bi[p - 1] = ti;
    }
  }
}

// ---------------- Kernel 1: kNN on pos (F=3), 4-way candidate split ----------------
__global__ __launch_bounds__(256) void k_knn1(const float* __restrict__ pos,
                                              int* __restrict__ idx1) {
  __shared__ float ps[6144];
  __shared__ float sqs[2048];
  __shared__ float md[640];
  __shared__ int mi[640];
  int tid = threadIdx.x;
  int b = blockIdx.x >> 5, qc = blockIdx.x & 31;
  const float* src = pos + b * 6144;
  for (int u = tid; u < 6144; u += 256) ps[u] = src[u];
  __syncthreads();
  for (int u = tid; u < 2048; u += 256) {
    float x = ps[u * 3], y = ps[u * 3 + 1], z = ps[u * 3 + 2];
    sqs[u] = fmaf(z, z, fmaf(y, y, x * x));
  }
  __syncthreads();
  int q = tid & 63, sub = tid >> 6;
  int qi = qc * 64 + q;
  float qx = ps[qi * 3], qy = ps[qi * 3 + 1], qz = ps[qi * 3 + 2];
  float qsq = sqs[qi];
  float bd[5] = {1e30f, 1e30f, 1e30f, 1e30f, 1e30f};
  int bi[5] = {0, 0, 0, 0, 0};
  int j0 = sub * 512;
  for (int j = j0; j < j0 + 512; ++j) {
    float px = ps[j * 3], py = ps[j * 3 + 1], pz = ps[j * 3 + 2];
    float dot = fmaf(qz, pz, fmaf(qy, py, qx * px));
    float d = (qsq + sqs[j]) - 2.0f * dot;
    knn_insert(bd, bi, d, j);
  }
  for (int half = 2; half >= 1; half >>= 1) {
    __syncthreads();
    if (sub >= half && sub < 2 * half) {
      int slot = (q * 2 + (sub - half)) * 5;
#pragma unroll
      for (int k = 0; k < 5; ++k) { md[slot + k] = bd[k]; mi[slot + k] = bi[k]; }
    }
    __syncthreads();
    if (sub < half) {
      int slot = (q * 2 + sub) * 5;
#pragma unroll
      for (int k = 0; k < 5; ++k) knn_insert(bd, bi, md[slot + k], mi[slot + k]);
    }
  }
  if (sub == 0) {
    int* op = idx1 + (b * 2048 + qi) * 5;
#pragma unroll
    for (int k = 0; k < 5; ++k) op[k] = bi[k];
  }
}

// ---------------- Kernel 2: EdgeConv1 -> x1t fp32 [b][f][n], sq, xb bf16 [n][0:64] ----------------
__global__ __launch_bounds__(256) void k_edge1(
    const float* __restrict__ pos, const int* __restrict__ idx1,
    const float* __restrict__ w1a, const float* __restrict__ b1a,
    const float* __restrict__ s1a, const float* __restrict__ h1a,
    const float* __restrict__ w1b, const float* __restrict__ b1b,
    const float* __restrict__ s1b, const float* __restrict__ h1b,
    const float* __restrict__ w1c, const float* __restrict__ b1c,
    const float* __restrict__ s1c, const float* __restrict__ h1c,
    float* __restrict__ x1t, float* __restrict__ sqo, __bf16* __restrict__ xb) {
  __shared__ float wA[384], wB[4096], wC[4096];
  __shared__ float cA[192], cB[192], cC[192];
  __shared__ float hb1[1024], hb2[1024];
  int tid = threadIdx.x;
  for (int u = tid; u < 384; u += 256) wA[u] = w1a[u];
  for (int u = tid; u < 4096; u += 256) { wB[u] = w1b[u]; wC[u] = w1c[u]; }
  if (tid < 64) {
    cA[tid] = b1a[tid]; cA[64 + tid] = s1a[tid]; cA[128 + tid] = h1a[tid];
    cB[tid] = b1b[tid]; cB[64 + tid] = s1b[tid]; cB[128 + tid] = h1b[tid];
    cC[tid] = b1c[tid]; cC[64 + tid] = s1c[tid]; cC[128 + tid] = h1c[tid];
  }
  __syncthreads();
  int c = tid & 63, pg = tid >> 6;
  int n0 = blockIdx.x * 16;
  int b = n0 >> 11;
  int nn[4];
  float xi[4][3];
#pragma unroll
  for (int pp = 0; pp < 4; ++pp) {
    nn[pp] = n0 + pg * 4 + pp;
    xi[pp][0] = pos[nn[pp] * 3];
    xi[pp][1] = pos[nn[pp] * 3 + 1];
    xi[pp][2] = pos[nn[pp] * 3 + 2];
  }
  float am[4] = {-3.4e38f, -3.4e38f, -3.4e38f, -3.4e38f};
  for (int k = 0; k < 5; ++k) {
#pragma unroll
    for (int pp = 0; pp < 4; ++pp) {
      int j = idx1[nn[pp] * 5 + k];
      int jr = (b << 11) + j;
      float e3 = pos[jr * 3] - xi[pp][0];
      float e4 = pos[jr * 3 + 1] - xi[pp][1];
      float e5 = pos[jr * 3 + 2] - xi[pp][2];
      float a = xi[pp][0] * wA[c];
      a = fmaf(xi[pp][1], wA[64 + c], a);
      a = fmaf(xi[pp][2], wA[128 + c], a);
      a = fmaf(e3, wA[192 + c], a);
      a = fmaf(e4, wA[256 + c], a);
      a = fmaf(e5, wA[320 + c], a);
      hb1[(pg * 4 + pp) * 64 + c] = relu_(a + cA[c]) * cA[64 + c] + cA[128 + c];
    }
    __syncthreads();
    {
      float a2[4] = {0, 0, 0, 0};
      for (int f = 0; f < 64; ++f) {
        float wv = wB[f * 64 + c];
#pragma unroll
        for (int pp = 0; pp < 4; ++pp)
          a2[pp] = fmaf(hb1[(pg * 4 + pp) * 64 + f], wv, a2[pp]);
      }
#pragma unroll
      for (int pp = 0; pp < 4; ++pp)
        hb2[(pg * 4 + pp) * 64 + c] = relu_(a2[pp] + cB[c]) * cB[64 + c] + cB[128 + c];
    }
    __syncthreads();
    {
      float a3[4] = {0, 0, 0, 0};
      for (int f = 0; f < 64; ++f) {
        float wv = wC[f * 64 + c];
#pragma unroll
        for (int pp = 0; pp < 4; ++pp)
          a3[pp] = fmaf(hb2[(pg * 4 + pp) * 64 + f], wv, a3[pp]);
      }
#pragma unroll
      for (int pp = 0; pp < 4; ++pp)
        am[pp] = fmaxf(am[pp], relu_(a3[pp] + cC[c]) * cC[64 + c] + cC[128 + c]);
    }
    __syncthreads();
  }
#pragma unroll
  for (int pp = 0; pp < 4; ++pp) {
    float v = am[pp];
    int nloc = nn[pp] & 2047;
    x1t[(b * 64 + c) * 2048 + nloc] = v;
    xb[(size_t)nn[pp] * 192 + c] = (__bf16)v;  // features 0..63 for final linear
    float s = v * v;
    s += __shfl_xor(s, 1);
    s += __shfl_xor(s, 2);
    s += __shfl_xor(s, 4);
    s += __shfl_xor(s, 8);
    s += __shfl_xor(s, 16);
    s += __shfl_xor(s, 32);
    if (c == 0) sqo[nn[pp]] = s;
  }
}

// ---------------- Kernel 3: kNN on x1 (F=64), GEMM-tiled (fp32, exact) ----------------
__global__ __launch_bounds__(256) void k_knn2(const float* __restrict__ x1t,
                                              const float* __restrict__ sq,
                                              int* __restrict__ idx2) {
  __shared__ __align__(16) float smem[8192];
  __shared__ float csq_s[64];
  float* As = smem;
  float* Bs = smem + 4096;
  float* md = smem;
  int* mi = (int*)(smem + 2560);
  int tid = threadIdx.x;
  int b = blockIdx.x >> 5, qc = blockIdx.x & 31;
  int q0 = qc * 64;
  int pg = tid & 15, cg = tid >> 4;
  {
    int fr = tid >> 4, c4 = tid & 15;
#pragma unroll
    for (int it = 0; it < 4; ++it) {
      int f = fr + it * 16;
      float4 g = *(const float4*)(x1t + (b * 64 + f) * 2048 + q0 + c4 * 4);
      *(float4*)(As + f * 64 + c4 * 4) = g;
    }
  }
  float qs[4];
#pragma unroll
  for (int ii = 0; ii < 4; ++ii) qs[ii] = sq[b * 2048 + q0 + pg * 4 + ii];
  float bd[4][5];
  int bi[4][5];
#pragma unroll
  for (int ii = 0; ii < 4; ++ii)
#pragma unroll
    for (int k = 0; k < 5; ++k) { bd[ii][k] = 1e30f; bi[ii][k] = 0; }
  for (int t = 0; t < 32; ++t) {
    __syncthreads();
    {
      int fr = tid >> 4, c4 = tid & 15;
#pragma unroll
      for (int it = 0; it < 4; ++it) {
        int f = fr + it * 16;
        float4 g = *(const float4*)(x1t + (b * 64 + f) * 2048 + t * 64 + c4 * 4);
        *(float4*)(Bs + f * 64 + c4 * 4) = g;
      }
      if (tid < 16)
        *(float4*)(csq_s + tid * 4) = *(const float4*)(sq + b * 2048 + t * 64 + tid * 4);
    }
    __syncthreads();
    float acc[4][4] = {{0, 0, 0, 0}, {0, 0, 0, 0}, {0, 0, 0, 0}, {0, 0, 0, 0}};
#pragma unroll 4
    for (int k = 0; k < 64; ++k) {
      float4 a4 = *(const float4*)(As + k * 64 + pg * 4);
      float4 b4 = *(const float4*)(Bs + k * 64 + cg * 4);
      float av[4] = {a4.x, a4.y, a4.z, a4.w};
      float bv[4] = {b4.x, b4.y, b4.z, b4.w};
#pragma unroll
      for (int ii = 0; ii < 4; ++ii)
#pragma unroll
        for (int jj = 0; jj < 4; ++jj)
          acc[ii][jj] = fmaf(av[ii], bv[jj], acc[ii][jj]);
    }
#pragma unroll
    for (int jj = 0; jj < 4; ++jj) {
      float cj = csq_s[cg * 4 + jj];
      int cid = t * 64 + cg * 4 + jj;
#pragma unroll
      for (int ii = 0; ii < 4; ++ii) {
        float d = (qs[ii] + cj) - 2.0f * acc[ii][jj];
        knn_insert(bd[ii], bi[ii], d, cid);
      }
    }
  }
  for (int half = 8; half >= 1; half >>= 1) {
    __syncthreads();
    if (cg >= half && cg < 2 * half) {
#pragma unroll
      for (int ii = 0; ii < 4; ++ii) {
        int slot = ((pg * 4 + ii) * 8 + (cg - half)) * 5;
#pragma unroll
        for (int k = 0; k < 5; ++k) { md[slot + k] = bd[ii][k]; mi[slot + k] = bi[ii][k]; }
      }
    }
    __syncthreads();
    if (cg < half) {
#pragma unroll
      for (int ii = 0; ii < 4; ++ii) {
        int slot = ((pg * 4 + ii) * 8 + cg) * 5;
#pragma unroll
        for (int k = 0; k < 5; ++k) knn_insert(bd[ii], bi[ii], md[slot + k], mi[slot + k]);
      }
    }
  }
  if (cg == 0) {
#pragma unroll
    for (int ii = 0; ii < 4; ++ii) {
      int* op = idx2 + (b * 2048 + q0 + pg * 4 + ii) * 5;
#pragma unroll
      for (int k = 0; k < 5; ++k) op[k] = bi[ii][k];
    }
  }
}

// ---------------- Kernel 4a: P = x1@(W1-W2), Q = x1@W2 -> bf16 outputs ----------------
__global__ __launch_bounds__(256) void k_pq(const float* __restrict__ x1t,
                                            const float* __restrict__ w2,
                                            __bf16* __restrict__ Pb,
                                            __bf16* __restrict__ Qb) {
  __shared__ __align__(16) float ins[4096];
  int tid = threadIdx.x;
  int pt = blockIdx.x >> 2, oc = blockIdx.x & 3;
  int n0 = pt * 64;
  int b = n0 >> 11, nloc = n0 & 2047;
  {
    int fr = tid >> 4, c4 = tid & 15;
#pragma unroll
    for (int it = 0; it < 4; ++it) {
      int f = fr + it * 16;
      float4 g = *(const float4*)(x1t + (b * 64 + f) * 2048 + nloc + c4 * 4);
      *(float4*)(ins + f * 64 + c4 * 4) = g;
    }
  }
  __syncthreads();
  int cg = tid >> 4, pg = tid & 15;
  int vcol = oc * 64 + cg * 4;
  bool isP = (oc < 2);
  int col = isP ? vcol : (vcol - 128);
  float acc[4][4] = {{0, 0, 0, 0}, {0, 0, 0, 0}, {0, 0, 0, 0}, {0, 0, 0, 0}};
#pragma unroll 4
  for (int k = 0; k < 64; ++k) {
    float4 av = *(const float4*)(ins + k * 64 + pg * 4);
    float a[4] = {av.x, av.y, av.z, av.w};
    float4 wBv = *(const float4*)(w2 + (64 + k) * 128 + col);
    float wv[4];
    if (isP) {
      float4 wAv = *(const float4*)(w2 + k * 128 + col);
      wv[0] = wAv.x - wBv.x; wv[1] = wAv.y - wBv.y;
      wv[2] = wAv.z - wBv.z; wv[3] = wAv.w - wBv.w;
    } else {
      wv[0] = wBv.x; wv[1] = wBv.y; wv[2] = wBv.z; wv[3] = wBv.w;
    }
#pragma unroll
    for (int ii = 0; ii < 4; ++ii)
#pragma unroll
      for (int jj = 0; jj < 4; ++jj)
        acc[ii][jj] = fmaf(a[ii], wv[jj], acc[ii][jj]);
  }
  __bf16* base = (isP ? Pb : Qb);
#pragma unroll
  for (int ii = 0; ii < 4; ++ii) {
    int n = n0 + pg * 4 + ii;
    __bf16 o[4];
#pragma unroll
    for (int jj = 0; jj < 4; ++jj) o[jj] = (__bf16)acc[ii][jj];
    *(uint2*)(base + (size_t)n * 128 + col) = *(const uint2*)o;
  }
}

// ---------------- Kernel 4p: repack wl (192x1024 fp32) -> MFMA-B frag order bf16 ----------------
// layout: [nt=8][ks=6][nb=8][lane=64][j=8]; elem = wl[ks*32+(lane>>4)*8+j][nt*128+nb*16+(lane&15)]
__global__ __launch_bounds__(256) void k_prep(const float* __restrict__ wl,
                                              __bf16* __restrict__ wlb) {
  int t = blockIdx.x * 256 + threadIdx.x;  // 0..24575
  int nt = t / 3072;
  int rem = t - nt * 3072;
  int ks = rem / 512;
  int rem2 = rem - ks * 512;
  int nb = rem2 >> 6, lane = rem2 & 63;
  int k0 = ks * 32 + (lane >> 4) * 8;
  int n = nt * 128 + nb * 16 + (lane & 15);
  __bf16 o[8];
#pragma unroll
  for (int j = 0; j < 8; ++j) o[j] = (__bf16)wl[(k0 + j) * 1024 + n];
  *(uint4*)(wlb + (size_t)t * 8) = *(const uint4*)o;
}

// ---------------- Kernel 4b: gather-max + activation -> xb bf16 [n][64:192] ----------------
__global__ __launch_bounds__(256) void k_gmax(const __bf16* __restrict__ Pb,
                                              const __bf16* __restrict__ Qb,
                                              const int* __restrict__ idx2,
                                              const float* __restrict__ b2,
                                              const float* __restrict__ s2,
                                              const float* __restrict__ h2v,
                                              __bf16* __restrict__ xb) {
  int tid = threadIdx.x;
  int c = tid & 127, p = tid >> 7;
  int n = blockIdx.x * 2 + p;
  int b = n >> 11;
  const int* ip = idx2 + n * 5;
  float m = -3.4e38f;
#pragma unroll
  for (int k = 0; k < 5; ++k) {
    int j = ip[k];
    m = fmaxf(m, (float)Qb[((size_t)(b * 2048 + j)) * 128 + c]);
  }
  float v = (float)Pb[(size_t)n * 128 + c] + m + b2[c];
  xb[(size_t)n * 192 + 64 + c] = (__bf16)(relu_(v) * s2[c] + h2v[c]);
}

// ---------------- Kernel 5: bf16 MFMA GEMM [65536x192]@[192x1024] fused point-max ----------------
// grid 4096 = 512 m-tiles x 8 n-tiles; block 256 = 4 waves (2x2 of 64x64)
__global__ __launch_bounds__(256) void k_linl_mfma(const __bf16* __restrict__ xb,
                                                   const __bf16* __restrict__ wlb,
                                                   float* __restrict__ pool_part) {
  __shared__ __align__(16) __bf16 Al[4096];  // [mb=8][lane=64][8] frag order
  __shared__ __align__(16) __bf16 Bl[4096];  // [nb=8][lane=64][8] frag order
  __shared__ float red[256];
  int tid = threadIdx.x;
  int w = tid >> 6, lane = tid & 63;
  int mt = blockIdx.x >> 3, nt = blockIdx.x & 7;
  int n0 = mt << 7;
  int wm = w & 1, wn = w >> 1;
  int quad = lane >> 4, lm = lane & 15;
  f32x4 acc[4][4];
#pragma unroll
  for (int i = 0; i < 4; ++i)
#pragma unroll
    for (int j = 0; j < 4; ++j) acc[i][j] = (f32x4){0.f, 0.f, 0.f, 0.f};
  for (int ks = 0; ks < 6; ++ks) {
    __syncthreads();
#pragma unroll
    for (int u = 0; u < 2; ++u) {
      int mb = w * 2 + u;
      const uint4* ga = (const uint4*)(xb + (size_t)(n0 + mb * 16 + lm) * 192 + ks * 32 + quad * 8);
      *(uint4*)(Al + (mb * 64 + lane) * 8) = *ga;
      const uint4* gb = (const uint4*)(wlb + ((((size_t)nt * 6 + ks) * 8 + mb) * 64 + lane) * 8);
      *(uint4*)(Bl + (mb * 64 + lane) * 8) = *gb;
    }
    __syncthreads();
    bf16x8 af[4], bfr[4];
#pragma unroll
    for (int i = 0; i < 4; ++i) {
      af[i] = *(const bf16x8*)(Al + ((wm * 4 + i) * 64 + lane) * 8);
      bfr[i] = *(const bf16x8*)(Bl + ((wn * 4 + i) * 64 + lane) * 8);
    }
#pragma unroll
    for (int i = 0; i < 4; ++i)
#pragma unroll
      for (int j = 0; j < 4; ++j)
        acc[i][j] = __builtin_amdgcn_mfma_f32_16x16x32_bf16(af[i], bfr[j], acc[i][j], 0, 0, 0);
  }
  // acc[i][j][r] = C[n0 + wm*64 + i*16 + quad*4 + r][nt*128 + wn*64 + j*16 + lm]
  float pm[4];
#pragma unroll
  for (int j = 0; j < 4; ++j) {
    float m = -3.4e38f;
#pragma unroll
    for (int i = 0; i < 4; ++i)
#pragma unroll
      for (int r = 0; r < 4; ++r) m = fmaxf(m, acc[i][j][r]);
    m = fmaxf(m, __shfl_xor(m, 16));  // reduce across quads (rows +16,+32,+48)
    m = fmaxf(m, __shfl_xor(m, 32));
    pm[j] = m;
  }
  __syncthreads();
  if (quad == 0) {
#pragma unroll
    for (int j = 0; j < 4; ++j) red[w * 64 + j * 16 + lm] = pm[j];
  }
  __syncthreads();
  if (tid < 128) {
    int wn2 = tid >> 6, cc = tid & 63;
    float v = fmaxf(red[(wn2 * 2) * 64 + cc], red[(wn2 * 2 + 1) * 64 + cc]);
    pool_part[(size_t)mt * 1024 + nt * 128 + wn2 * 64 + cc] = v;
  }
}

// ---------------- Kernel 6: head MLP (16-way pool-merge + activation first) ----------------
__global__ __launch_bounds__(256) void k_head(
    const float* __restrict__ pool_part, const float* __restrict__ bl,
    const float* __restrict__ sl, const float* __restrict__ hl,
    const float* __restrict__ wm1, const float* __restrict__ bm1,
    const float* __restrict__ sm1, const float* __restrict__ hm1,
    const float* __restrict__ wm2, const float* __restrict__ bm2,
    const float* __restrict__ sm2, const float* __restrict__ hm2,
    const float* __restrict__ wout, const float* __restrict__ bout,
    float* __restrict__ out) {
  __shared__ float p_s[1024], h1_s[512], h2_s[256];
  int b = blockIdx.x, tid = threadIdx.x;
  for (int c = tid; c < 1024; c += 256) {
    float m = -3.4e38f;
#pragma unroll 4
    for (int t = 0; t < 16; ++t)
      m = fmaxf(m, pool_part[(size_t)(b * 16 + t) * 1024 + c]);
    p_s[c] = relu_(m + bl[c]) * sl[c] + hl[c];
  }
  __syncthreads();
  for (int c = tid; c < 512; c += 256) {
    float a0 = 0, a1 = 0, a2 = 0, a3 = 0;
    for (int f = 0; f < 1024; f += 4) {
      a0 = fmaf(p_s[f], wm1[f * 512 + c], a0);
      a1 = fmaf(p_s[f + 1], wm1[(f + 1) * 512 + c], a1);
      a2 = fmaf(p_s[f + 2], wm1[(f + 2) * 512 + c], a2);
      a3 = fmaf(p_s[f + 3], wm1[(f + 3) * 512 + c], a3);
    }
    float a = (a0 + a1) + (a2 + a3);
    h1_s[c] = relu_(a + bm1[c]) * sm1[c] + hm1[c];
  }
  __syncthreads();
  if (tid < 256) {
    float a0 = 0, a1 = 0, a2 = 0, a3 = 0;
    for (int f = 0; f < 512; f += 4) {
      a0 = fmaf(h1_s[f], wm2[f * 256 + tid], a0);
      a1 = fmaf(h1_s[f + 1], wm2[(f + 1) * 256 + tid], a1);
      a2 = fmaf(h1_s[f + 2], wm2[(f + 2) * 256 + tid], a2);
      a3 = fmaf(h1_s[f + 3], wm2[(f + 3) * 256 + tid], a3);
    }
    float a = (a0 + a1) + (a2 + a3);
    h2_s[tid] = relu_(a + bm2[tid]) * sm2[tid] + hm2[tid];
  }
  __syncthreads();
  if (tid < 2) {
    float a0 = 0, a1 = 0;
    for (int f = 0; f < 256; f += 2) {
      a0 = fmaf(h2_s[f], wout[f * 2 + tid], a0);
      a1 = fmaf(h2_s[f + 1], wout[(f + 1) * 2 + tid], a1);
    }
    out[b * 2 + tid] = (a0 + a1) + bout[tid];
  }
}

extern "C" void kernel_launch(void* const* d_in, const int* in_sizes, int n_in,
                              void* d_out, int out_size, void* d_ws, size_t ws_size,
                              hipStream_t stream) {
  const float* pos = (const float*)d_in[0];
  const float* w1a = (const float*)d_in[1];
  const float* b1a = (const float*)d_in[2];
  const float* s1a = (const float*)d_in[3];
  const float* h1a = (const float*)d_in[4];
  const float* w1b = (const float*)d_in[5];
  const float* b1b = (const float*)d_in[6];
  const float* s1b = (const float*)d_in[7];
  const float* h1b = (const float*)d_in[8];
  const float* w1c = (const float*)d_in[9];
  const float* b1c = (const float*)d_in[10];
  const float* s1c = (const float*)d_in[11];
  const float* h1c = (const float*)d_in[12];
  const float* w2 = (const float*)d_in[13];
  const float* b2 = (const float*)d_in[14];
  const float* s2 = (const float*)d_in[15];
  const float* h2 = (const float*)d_in[16];
  const float* wl = (const float*)d_in[17];
  const float* bl = (const float*)d_in[18];
  const float* sl = (const float*)d_in[19];
  const float* hl = (const float*)d_in[20];
  const float* wm1 = (const float*)d_in[21];
  const float* bm1 = (const float*)d_in[22];
  const float* sm1 = (const float*)d_in[23];
  const float* hm1 = (const float*)d_in[24];
  const float* wm2 = (const float*)d_in[25];
  const float* bm2 = (const float*)d_in[26];
  const float* sm2 = (const float*)d_in[27];
  const float* hm2 = (const float*)d_in[28];
  const float* wout = (const float*)d_in[29];
  const float* bout = (const float*)d_in[30];
  float* out = (float*)d_out;

  // workspace (float units): x1t | Pb | Qb | xb | idx | sq   (~77 MB)
  float* x1t = (float*)d_ws;                    // 4,194,304 f (dead after k_pq)
  float* PbF = x1t + 4194304;                   // 4,194,304 f (bf16 P)
  float* QbF = PbF + 4194304;                   // 4,194,304 f (bf16 Q)
  float* xbF = QbF + 4194304;                   // 6,291,456 f (bf16 xb[65536][192])
  int* idx = (int*)(xbF + 6291456);             // 327,680
  float* sq = (float*)(idx + 327680);           // 65,536
  __bf16* Pb = (__bf16*)PbF;
  __bf16* Qb = (__bf16*)QbF;
  __bf16* xb = (__bf16*)xbF;
  // aliases over dead x1t (valid after k_pq):
  __bf16* wlb = (__bf16*)x1t;                   // 196,608 bf16 = 384 KB
  float* pool_part = x1t + 131072;              // 512 KB offset; 512x1024 f = 2 MB

  k_knn1<<<1024, 256, 0, stream>>>(pos, idx);
  k_edge1<<<4096, 256, 0, stream>>>(pos, idx, w1a, b1a, s1a, h1a, w1b, b1b, s1b,
                                    h1b, w1c, b1c, s1c, h1c, x1t, sq, xb);
  k_knn2<<<1024, 256, 0, stream>>>(x1t, sq, idx);
  k_pq<<<4096, 256, 0, stream>>>(x1t, w2, Pb, Qb);
  k_prep<<<96, 256, 0, stream>>>(wl, wlb);  // after k_pq: x1t region is dead
  k_gmax<<<32768, 256, 0, stream>>>(Pb, Qb, idx, b2, s2, h2, xb);
  k_linl_mfma<<<4096, 256, 0, stream>>>(xb, wlb, pool_part);
  k_head<<<32, 256, 0, stream>>>(pool_part, bl, sl, hl, wm1, bm1, sm1, hm1, wm2,
                                 bm2, sm2, hm2, wout, bout, out);
}

// Round 4
// 747.572 us; speedup vs baseline: 2.3885x; 1.2264x over previous
//
#include <hip/hip_runtime.h>

#define DEV __device__ __forceinline__
DEV float relu_(float x) { return fmaxf(x, 0.0f); }

typedef __attribute__((ext_vector_type(4))) float f32x4;
typedef __attribute__((ext_vector_type(8))) __bf16 bf16x8;

DEV void knn_insert(float (&bd)[5], int (&bi)[5], float d, int j) {
  if (d >= bd[4]) return;
  bd[4] = d; bi[4] = j;
#pragma unroll
  for (int p = 4; p > 0; --p) {
    if (bd[p] < bd[p - 1]) {
      float td = bd[p]; bd[p] = bd[p - 1]; bd[p - 1] = td;
      int ti = bi[p]; bi[p] = bi[p - 1]; bi[p - 1] = ti;
    }
  }
}

// ---------------- Kernel 1: kNN on pos (F=3), 4-way candidate split ----------------
__global__ __launch_bounds__(256) void k_knn1(const float* __restrict__ pos,
                                              int* __restrict__ idx1) {
  __shared__ float ps[6144];
  __shared__ float sqs[2048];
  __shared__ float md[640];
  __shared__ int mi[640];
  int tid = threadIdx.x;
  int b = blockIdx.x >> 5, qc = blockIdx.x & 31;
  const float* src = pos + b * 6144;
  for (int u = tid; u < 6144; u += 256) ps[u] = src[u];
  __syncthreads();
  for (int u = tid; u < 2048; u += 256) {
    float x = ps[u * 3], y = ps[u * 3 + 1], z = ps[u * 3 + 2];
    sqs[u] = fmaf(z, z, fmaf(y, y, x * x));
  }
  __syncthreads();
  int q = tid & 63, sub = tid >> 6;
  int qi = qc * 64 + q;
  float qx = ps[qi * 3], qy = ps[qi * 3 + 1], qz = ps[qi * 3 + 2];
  float qsq = sqs[qi];
  float bd[5] = {1e30f, 1e30f, 1e30f, 1e30f, 1e30f};
  int bi[5] = {0, 0, 0, 0, 0};
  int j0 = sub * 512;
  for (int j = j0; j < j0 + 512; ++j) {
    float px = ps[j * 3], py = ps[j * 3 + 1], pz = ps[j * 3 + 2];
    float dot = fmaf(qz, pz, fmaf(qy, py, qx * px));
    float d = (qsq + sqs[j]) - 2.0f * dot;
    knn_insert(bd, bi, d, j);
  }
  for (int half = 2; half >= 1; half >>= 1) {
    __syncthreads();
    if (sub >= half && sub < 2 * half) {
      int slot = (q * 2 + (sub - half)) * 5;
#pragma unroll
      for (int k = 0; k < 5; ++k) { md[slot + k] = bd[k]; mi[slot + k] = bi[k]; }
    }
    __syncthreads();
    if (sub < half) {
      int slot = (q * 2 + sub) * 5;
#pragma unroll
      for (int k = 0; k < 5; ++k) knn_insert(bd, bi, md[slot + k], mi[slot + k]);
    }
  }
  if (sub == 0) {
    int* op = idx1 + (b * 2048 + qi) * 5;
#pragma unroll
    for (int k = 0; k < 5; ++k) op[k] = bi[k];
  }
}

// ---------------- Kernel 2: EdgeConv1 -> xh/xl bf16 [n][64], sq fp32, xb[0:64] ----------------
__global__ __launch_bounds__(256) void k_edge1(
    const float* __restrict__ pos, const int* __restrict__ idx1,
    const float* __restrict__ w1a, const float* __restrict__ b1a,
    const float* __restrict__ s1a, const float* __restrict__ h1a,
    const float* __restrict__ w1b, const float* __restrict__ b1b,
    const float* __restrict__ s1b, const float* __restrict__ h1b,
    const float* __restrict__ w1c, const float* __restrict__ b1c,
    const float* __restrict__ s1c, const float* __restrict__ h1c,
    __bf16* __restrict__ xh, __bf16* __restrict__ xl,
    float* __restrict__ sqo, __bf16* __restrict__ xb) {
  __shared__ float wA[384], wB[4096], wC[4096];
  __shared__ float cA[192], cB[192], cC[192];
  __shared__ float hb1[1024], hb2[1024];
  int tid = threadIdx.x;
  for (int u = tid; u < 384; u += 256) wA[u] = w1a[u];
  for (int u = tid; u < 4096; u += 256) { wB[u] = w1b[u]; wC[u] = w1c[u]; }
  if (tid < 64) {
    cA[tid] = b1a[tid]; cA[64 + tid] = s1a[tid]; cA[128 + tid] = h1a[tid];
    cB[tid] = b1b[tid]; cB[64 + tid] = s1b[tid]; cB[128 + tid] = h1b[tid];
    cC[tid] = b1c[tid]; cC[64 + tid] = s1c[tid]; cC[128 + tid] = h1c[tid];
  }
  __syncthreads();
  int c = tid & 63, pg = tid >> 6;
  int n0 = blockIdx.x * 16;
  int b = n0 >> 11;
  int nn[4];
  float xi[4][3];
#pragma unroll
  for (int pp = 0; pp < 4; ++pp) {
    nn[pp] = n0 + pg * 4 + pp;
    xi[pp][0] = pos[nn[pp] * 3];
    xi[pp][1] = pos[nn[pp] * 3 + 1];
    xi[pp][2] = pos[nn[pp] * 3 + 2];
  }
  float am[4] = {-3.4e38f, -3.4e38f, -3.4e38f, -3.4e38f};
  for (int k = 0; k < 5; ++k) {
#pragma unroll
    for (int pp = 0; pp < 4; ++pp) {
      int j = idx1[nn[pp] * 5 + k];
      int jr = (b << 11) + j;
      float e3 = pos[jr * 3] - xi[pp][0];
      float e4 = pos[jr * 3 + 1] - xi[pp][1];
      float e5 = pos[jr * 3 + 2] - xi[pp][2];
      float a = xi[pp][0] * wA[c];
      a = fmaf(xi[pp][1], wA[64 + c], a);
      a = fmaf(xi[pp][2], wA[128 + c], a);
      a = fmaf(e3, wA[192 + c], a);
      a = fmaf(e4, wA[256 + c], a);
      a = fmaf(e5, wA[320 + c], a);
      hb1[(pg * 4 + pp) * 64 + c] = relu_(a + cA[c]) * cA[64 + c] + cA[128 + c];
    }
    __syncthreads();
    {
      float a2[4] = {0, 0, 0, 0};
      for (int f = 0; f < 64; ++f) {
        float wv = wB[f * 64 + c];
#pragma unroll
        for (int pp = 0; pp < 4; ++pp)
          a2[pp] = fmaf(hb1[(pg * 4 + pp) * 64 + f], wv, a2[pp]);
      }
#pragma unroll
      for (int pp = 0; pp < 4; ++pp)
        hb2[(pg * 4 + pp) * 64 + c] = relu_(a2[pp] + cB[c]) * cB[64 + c] + cB[128 + c];
    }
    __syncthreads();
    {
      float a3[4] = {0, 0, 0, 0};
      for (int f = 0; f < 64; ++f) {
        float wv = wC[f * 64 + c];
#pragma unroll
        for (int pp = 0; pp < 4; ++pp)
          a3[pp] = fmaf(hb2[(pg * 4 + pp) * 64 + f], wv, a3[pp]);
      }
#pragma unroll
      for (int pp = 0; pp < 4; ++pp)
        am[pp] = fmaxf(am[pp], relu_(a3[pp] + cC[c]) * cC[64 + c] + cC[128 + c]);
    }
    __syncthreads();
  }
#pragma unroll
  for (int pp = 0; pp < 4; ++pp) {
    float v = am[pp];
    __bf16 h = (__bf16)v;
    __bf16 l = (__bf16)(v - (float)h);
    size_t nbase = (size_t)nn[pp] * 64 + c;
    xh[nbase] = h;
    xl[nbase] = l;
    xb[(size_t)nn[pp] * 192 + c] = h;  // features 0..63 for final linear (bf16 round of v)
    float s = v * v;
    s += __shfl_xor(s, 1);
    s += __shfl_xor(s, 2);
    s += __shfl_xor(s, 4);
    s += __shfl_xor(s, 8);
    s += __shfl_xor(s, 16);
    s += __shfl_xor(s, 32);
    if (c == 0) sqo[nn[pp]] = s;
  }
}

// ---------------- Kernel 3: kNN on x1 via MFMA hi/lo split ----------------
// grid 1024 (32 b x 32 q-chunks of 64); block 256 = 4 waves, wave w owns queries w*16..w*16+15
__global__ __launch_bounds__(256) void k_knn2(const __bf16* __restrict__ xh,
                                              const __bf16* __restrict__ xl,
                                              const float* __restrict__ sq,
                                              int* __restrict__ idx2) {
  __shared__ __align__(16) __bf16 Bh[64 * 72];  // cand tile hi, stride 72 (pad)
  __shared__ __align__(16) __bf16 Bl[64 * 72];  // cand tile lo
  __shared__ float sqs[2048];
  int tid = threadIdx.x;
  int w = tid >> 6, lane = tid & 63;
  int quad = lane >> 4, lm = lane & 15;
  int b = blockIdx.x >> 5, qc = blockIdx.x & 31;
  int q0 = qc * 64;
  size_t bb = (size_t)b * 2048;
  for (int u = tid; u < 512; u += 256)
    *(float4*)(sqs + u * 4) = *(const float4*)(sq + bb + u * 4);
  // A-frags (registers, reused all tiles): query row m = lm for this wave's tile
  const __bf16* qh = xh + (bb + q0 + w * 16 + lm) * 64 + quad * 8;
  const __bf16* ql = xl + (bb + q0 + w * 16 + lm) * 64 + quad * 8;
  bf16x8 Ah0 = *(const bf16x8*)(qh);
  bf16x8 Ah1 = *(const bf16x8*)(qh + 32);
  bf16x8 Al0 = *(const bf16x8*)(ql);
  bf16x8 Al1 = *(const bf16x8*)(ql + 32);
  __syncthreads();
  float qsq[4];
#pragma unroll
  for (int r = 0; r < 4; ++r) qsq[r] = sqs[q0 + w * 16 + quad * 4 + r];
  float bd[4][5];
  int bi[4][5];
#pragma unroll
  for (int r = 0; r < 4; ++r)
#pragma unroll
    for (int k = 0; k < 5; ++k) { bd[r][k] = 1e30f; bi[r][k] = 0; }
  for (int ct = 0; ct < 32; ++ct) {
    // stage 64 candidates (hi+lo) coalesced; LDS stride 72 keeps frag reads conflict-free
#pragma unroll
    for (int pass = 0; pass < 2; ++pass) {
      int unit = pass * 256 + tid;  // 0..511
      int n = unit >> 3, cc = unit & 7;
      const __bf16* gsrc = xh + (bb + ct * 64 + n) * 64 + cc * 8;
      const __bf16* gsrl = xl + (bb + ct * 64 + n) * 64 + cc * 8;
      *(uint4*)(Bh + n * 72 + cc * 8) = *(const uint4*)gsrc;
      *(uint4*)(Bl + n * 72 + cc * 8) = *(const uint4*)gsrl;
    }
    __syncthreads();
#pragma unroll
    for (int nt = 0; nt < 4; ++nt) {
      const __bf16* bph = Bh + (nt * 16 + lm) * 72 + quad * 8;
      const __bf16* bpl = Bl + (nt * 16 + lm) * 72 + quad * 8;
      bf16x8 Bh0 = *(const bf16x8*)(bph);
      bf16x8 Bh1 = *(const bf16x8*)(bph + 32);
      bf16x8 Bl0 = *(const bf16x8*)(bpl);
      bf16x8 Bl1 = *(const bf16x8*)(bpl + 32);
      f32x4 acc = {0.f, 0.f, 0.f, 0.f};
      acc = __builtin_amdgcn_mfma_f32_16x16x32_bf16(Ah0, Bh0, acc, 0, 0, 0);
      acc = __builtin_amdgcn_mfma_f32_16x16x32_bf16(Ah1, Bh1, acc, 0, 0, 0);
      acc = __builtin_amdgcn_mfma_f32_16x16x32_bf16(Ah0, Bl0, acc, 0, 0, 0);
      acc = __builtin_amdgcn_mfma_f32_16x16x32_bf16(Ah1, Bl1, acc, 0, 0, 0);
      acc = __builtin_amdgcn_mfma_f32_16x16x32_bf16(Al0, Bh0, acc, 0, 0, 0);
      acc = __builtin_amdgcn_mfma_f32_16x16x32_bf16(Al1, Bh1, acc, 0, 0, 0);
      int cid = ct * 64 + nt * 16 + lm;
      float csq = sqs[cid];
#pragma unroll
      for (int r = 0; r < 4; ++r) {
        float d = (qsq[r] + csq) - 2.0f * acc[r];
        knn_insert(bd[r], bi[r], d, cid);
      }
    }
    __syncthreads();
  }
  // merge the 16 lm-partials per row via shuffle butterfly (stays within quad group)
  for (int m = 1; m <= 8; m <<= 1) {
#pragma unroll
    for (int r = 0; r < 4; ++r) {
      float od[5]; int oi[5];
#pragma unroll
      for (int k = 0; k < 5; ++k) {
        od[k] = __shfl_xor(bd[r][k], m);
        oi[k] = __shfl_xor(bi[r][k], m);
      }
#pragma unroll
      for (int k = 0; k < 5; ++k) knn_insert(bd[r], bi[r], od[k], oi[k]);
    }
  }
  if (lm == 0) {
#pragma unroll
    for (int r = 0; r < 4; ++r) {
      int qi = q0 + w * 16 + quad * 4 + r;
      int* op = idx2 + (bb + qi) * 5;
#pragma unroll
      for (int k = 0; k < 5; ++k) op[k] = bi[r][k];
    }
  }
}

// ---------------- Kernel 4a: P = x1@(W1-W2), Q = x1@W2 (x1 = hi+lo) ----------------
__global__ __launch_bounds__(256) void k_pq(const __bf16* __restrict__ xh,
                                            const __bf16* __restrict__ xl,
                                            const float* __restrict__ w2,
                                            __bf16* __restrict__ Pb,
                                            __bf16* __restrict__ Qb) {
  __shared__ __align__(16) float ins[4096];  // [k(64)][p(64)]
  int tid = threadIdx.x;
  int pt = blockIdx.x >> 2, oc = blockIdx.x & 3;
  int n0 = pt * 64;  // global point base
#pragma unroll
  for (int pass = 0; pass < 2; ++pass) {
    int unit = pass * 256 + tid;  // 0..511
    int n = unit >> 3, cc = unit & 7;
    bf16x8 h = *(const bf16x8*)(xh + ((size_t)(n0 + n)) * 64 + cc * 8);
    bf16x8 l = *(const bf16x8*)(xl + ((size_t)(n0 + n)) * 64 + cc * 8);
#pragma unroll
    for (int j = 0; j < 8; ++j)
      ins[(cc * 8 + j) * 64 + n] = (float)h[j] + (float)l[j];
  }
  __syncthreads();
  int cg = tid >> 4, pg = tid & 15;
  int vcol = oc * 64 + cg * 4;
  bool isP = (oc < 2);
  int col = isP ? vcol : (vcol - 128);
  float acc[4][4] = {{0, 0, 0, 0}, {0, 0, 0, 0}, {0, 0, 0, 0}, {0, 0, 0, 0}};
#pragma unroll 4
  for (int k = 0; k < 64; ++k) {
    float4 av = *(const float4*)(ins + k * 64 + pg * 4);
    float a[4] = {av.x, av.y, av.z, av.w};
    float4 wBv = *(const float4*)(w2 + (64 + k) * 128 + col);
    float wv[4];
    if (isP) {
      float4 wAv = *(const float4*)(w2 + k * 128 + col);
      wv[0] = wAv.x - wBv.x; wv[1] = wAv.y - wBv.y;
      wv[2] = wAv.z - wBv.z; wv[3] = wAv.w - wBv.w;
    } else {
      wv[0] = wBv.x; wv[1] = wBv.y; wv[2] = wBv.z; wv[3] = wBv.w;
    }
#pragma unroll
    for (int ii = 0; ii < 4; ++ii)
#pragma unroll
      for (int jj = 0; jj < 4; ++jj)
        acc[ii][jj] = fmaf(a[ii], wv[jj], acc[ii][jj]);
  }
  __bf16* base = (isP ? Pb : Qb);
#pragma unroll
  for (int ii = 0; ii < 4; ++ii) {
    int n = n0 + pg * 4 + ii;
    __bf16 o[4];
#pragma unroll
    for (int jj = 0; jj < 4; ++jj) o[jj] = (__bf16)acc[ii][jj];
    *(uint2*)(base + (size_t)n * 128 + col) = *(const uint2*)o;
  }
}

// ---------------- Kernel 4p: repack wl (192x1024 fp32) -> MFMA-B frag order bf16 ----------------
__global__ __launch_bounds__(256) void k_prep(const float* __restrict__ wl,
                                              __bf16* __restrict__ wlb) {
  int t = blockIdx.x * 256 + threadIdx.x;  // 0..24575
  int nt = t / 3072;
  int rem = t - nt * 3072;
  int ks = rem / 512;
  int rem2 = rem - ks * 512;
  int nb = rem2 >> 6, lane = rem2 & 63;
  int k0 = ks * 32 + (lane >> 4) * 8;
  int n = nt * 128 + nb * 16 + (lane & 15);
  __bf16 o[8];
#pragma unroll
  for (int j = 0; j < 8; ++j) o[j] = (__bf16)wl[(k0 + j) * 1024 + n];
  *(uint4*)(wlb + (size_t)t * 8) = *(const uint4*)o;
}

// ---------------- Kernel 4b: gather-max + activation -> xb bf16 [n][64:192] ----------------
__global__ __launch_bounds__(256) void k_gmax(const __bf16* __restrict__ Pb,
                                              const __bf16* __restrict__ Qb,
                                              const int* __restrict__ idx2,
                                              const float* __restrict__ b2,
                                              const float* __restrict__ s2,
                                              const float* __restrict__ h2v,
                                              __bf16* __restrict__ xb) {
  int tid = threadIdx.x;
  int c = tid & 127, p = tid >> 7;
  int n = blockIdx.x * 2 + p;
  int b = n >> 11;
  const int* ip = idx2 + n * 5;
  float m = -3.4e38f;
#pragma unroll
  for (int k = 0; k < 5; ++k) {
    int j = ip[k];
    m = fmaxf(m, (float)Qb[((size_t)(b * 2048 + j)) * 128 + c]);
  }
  float v = (float)Pb[(size_t)n * 128 + c] + m + b2[c];
  xb[(size_t)n * 192 + 64 + c] = (__bf16)(relu_(v) * s2[c] + h2v[c]);
}

// ---------------- Kernel 5: bf16 MFMA GEMM [65536x192]@[192x1024] fused point-max ----------------
__global__ __launch_bounds__(256) void k_linl_mfma(const __bf16* __restrict__ xb,
                                                   const __bf16* __restrict__ wlb,
                                                   float* __restrict__ pool_part) {
  __shared__ __align__(16) __bf16 Al[4096];
  __shared__ __align__(16) __bf16 Bl[4096];
  __shared__ float red[256];
  int tid = threadIdx.x;
  int w = tid >> 6, lane = tid & 63;
  int mt = blockIdx.x >> 3, nt = blockIdx.x & 7;
  int n0 = mt << 7;
  int wm = w & 1, wn = w >> 1;
  int quad = lane >> 4, lm = lane & 15;
  f32x4 acc[4][4];
#pragma unroll
  for (int i = 0; i < 4; ++i)
#pragma unroll
    for (int j = 0; j < 4; ++j) acc[i][j] = (f32x4){0.f, 0.f, 0.f, 0.f};
  for (int ks = 0; ks < 6; ++ks) {
    __syncthreads();
#pragma unroll
    for (int u = 0; u < 2; ++u) {
      int mb = w * 2 + u;
      const uint4* ga = (const uint4*)(xb + (size_t)(n0 + mb * 16 + lm) * 192 + ks * 32 + quad * 8);
      *(uint4*)(Al + (mb * 64 + lane) * 8) = *ga;
      const uint4* gb = (const uint4*)(wlb + ((((size_t)nt * 6 + ks) * 8 + mb) * 64 + lane) * 8);
      *(uint4*)(Bl + (mb * 64 + lane) * 8) = *gb;
    }
    __syncthreads();
    bf16x8 af[4], bfr[4];
#pragma unroll
    for (int i = 0; i < 4; ++i) {
      af[i] = *(const bf16x8*)(Al + ((wm * 4 + i) * 64 + lane) * 8);
      bfr[i] = *(const bf16x8*)(Bl + ((wn * 4 + i) * 64 + lane) * 8);
    }
#pragma unroll
    for (int i = 0; i < 4; ++i)
#pragma unroll
      for (int j = 0; j < 4; ++j)
        acc[i][j] = __builtin_amdgcn_mfma_f32_16x16x32_bf16(af[i], bfr[j], acc[i][j], 0, 0, 0);
  }
  float pm[4];
#pragma unroll
  for (int j = 0; j < 4; ++j) {
    float m = -3.4e38f;
#pragma unroll
    for (int i = 0; i < 4; ++i)
#pragma unroll
      for (int r = 0; r < 4; ++r) m = fmaxf(m, acc[i][j][r]);
    m = fmaxf(m, __shfl_xor(m, 16));
    m = fmaxf(m, __shfl_xor(m, 32));
    pm[j] = m;
  }
  __syncthreads();
  if (quad == 0) {
#pragma unroll
    for (int j = 0; j < 4; ++j) red[w * 64 + j * 16 + lm] = pm[j];
  }
  __syncthreads();
  if (tid < 128) {
    int wn2 = tid >> 6, cc = tid & 63;
    float v = fmaxf(red[(wn2 * 2) * 64 + cc], red[(wn2 * 2 + 1) * 64 + cc]);
    pool_part[(size_t)mt * 1024 + nt * 128 + wn2 * 64 + cc] = v;
  }
}

// ---------------- Kernel 6: head MLP ----------------
__global__ __launch_bounds__(256) void k_head(
    const float* __restrict__ pool_part, const float* __restrict__ bl,
    const float* __restrict__ sl, const float* __restrict__ hl,
    const float* __restrict__ wm1, const float* __restrict__ bm1,
    const float* __restrict__ sm1, const float* __restrict__ hm1,
    const float* __restrict__ wm2, const float* __restrict__ bm2,
    const float* __restrict__ sm2, const float* __restrict__ hm2,
    const float* __restrict__ wout, const float* __restrict__ bout,
    float* __restrict__ out) {
  __shared__ float p_s[1024], h1_s[512], h2_s[256];
  int b = blockIdx.x, tid = threadIdx.x;
  for (int c = tid; c < 1024; c += 256) {
    float m = -3.4e38f;
#pragma unroll 4
    for (int t = 0; t < 16; ++t)
      m = fmaxf(m, pool_part[(size_t)(b * 16 + t) * 1024 + c]);
    p_s[c] = relu_(m + bl[c]) * sl[c] + hl[c];
  }
  __syncthreads();
  for (int c = tid; c < 512; c += 256) {
    float a0 = 0, a1 = 0, a2 = 0, a3 = 0;
    for (int f = 0; f < 1024; f += 4) {
      a0 = fmaf(p_s[f], wm1[f * 512 + c], a0);
      a1 = fmaf(p_s[f + 1], wm1[(f + 1) * 512 + c], a1);
      a2 = fmaf(p_s[f + 2], wm1[(f + 2) * 512 + c], a2);
      a3 = fmaf(p_s[f + 3], wm1[(f + 3) * 512 + c], a3);
    }
    float a = (a0 + a1) + (a2 + a3);
    h1_s[c] = relu_(a + bm1[c]) * sm1[c] + hm1[c];
  }
  __syncthreads();
  if (tid < 256) {
    float a0 = 0, a1 = 0, a2 = 0, a3 = 0;
    for (int f = 0; f < 512; f += 4) {
      a0 = fmaf(h1_s[f], wm2[f * 256 + tid], a0);
      a1 = fmaf(h1_s[f + 1], wm2[(f + 1) * 256 + tid], a1);
      a2 = fmaf(h1_s[f + 2], wm2[(f + 2) * 256 + tid], a2);
      a3 = fmaf(h1_s[f + 3], wm2[(f + 3) * 256 + tid], a3);
    }
    float a = (a0 + a1) + (a2 + a3);
    h2_s[tid] = relu_(a + bm2[tid]) * sm2[tid] + hm2[tid];
  }
  __syncthreads();
  if (tid < 2) {
    float a0 = 0, a1 = 0;
    for (int f = 0; f < 256; f += 2) {
      a0 = fmaf(h2_s[f], wout[f * 2 + tid], a0);
      a1 = fmaf(h2_s[f + 1], wout[(f + 1) * 2 + tid], a1);
    }
    out[b * 2 + tid] = (a0 + a1) + bout[tid];
  }
}

extern "C" void kernel_launch(void* const* d_in, const int* in_sizes, int n_in,
                              void* d_out, int out_size, void* d_ws, size_t ws_size,
                              hipStream_t stream) {
  const float* pos = (const float*)d_in[0];
  const float* w1a = (const float*)d_in[1];
  const float* b1a = (const float*)d_in[2];
  const float* s1a = (const float*)d_in[3];
  const float* h1a = (const float*)d_in[4];
  const float* w1b = (const float*)d_in[5];
  const float* b1b = (const float*)d_in[6];
  const float* s1b = (const float*)d_in[7];
  const float* h1b = (const float*)d_in[8];
  const float* w1c = (const float*)d_in[9];
  const float* b1c = (const float*)d_in[10];
  const float* s1c = (const float*)d_in[11];
  const float* h1c = (const float*)d_in[12];
  const float* w2 = (const float*)d_in[13];
  const float* b2 = (const float*)d_in[14];
  const float* s2 = (const float*)d_in[15];
  const float* h2 = (const float*)d_in[16];
  const float* wl = (const float*)d_in[17];
  const float* bl = (const float*)d_in[18];
  const float* sl = (const float*)d_in[19];
  const float* hl = (const float*)d_in[20];
  const float* wm1 = (const float*)d_in[21];
  const float* bm1 = (const float*)d_in[22];
  const float* sm1 = (const float*)d_in[23];
  const float* hm1 = (const float*)d_in[24];
  const float* wm2 = (const float*)d_in[25];
  const float* bm2 = (const float*)d_in[26];
  const float* sm2 = (const float*)d_in[27];
  const float* hm2 = (const float*)d_in[28];
  const float* wout = (const float*)d_in[29];
  const float* bout = (const float*)d_in[30];
  float* out = (float*)d_out;

  // workspace (float units): xh | xl | Pb | Qb | xb | idx | sq   (~77 MB)
  float* base = (float*)d_ws;
  __bf16* xh = (__bf16*)base;                   // 4,194,304 bf16 (2,097,152 f)
  __bf16* xl = (__bf16*)(base + 2097152);       // 4,194,304 bf16
  float* PbF = base + 4194304;                  // bf16 P: 8,388,608 bf16 (16 MB)
  float* QbF = PbF + 4194304;                   // bf16 Q
  float* xbF = QbF + 4194304;                   // bf16 xb[65536][192]
  int* idx = (int*)(xbF + 6291456);             // 327,680 ints
  float* sq = (float*)(idx + 327680);           // 65,536 f
  __bf16* Pb = (__bf16*)PbF;
  __bf16* Qb = (__bf16*)QbF;
  __bf16* xb = (__bf16*)xbF;
  // aliases over xh/xl (dead after k_pq):
  __bf16* wlb = (__bf16*)base;                  // 196,608 bf16
  float* pool_part = base + 131072;             // 512x1024 f

  k_knn1<<<1024, 256, 0, stream>>>(pos, idx);
  k_edge1<<<4096, 256, 0, stream>>>(pos, idx, w1a, b1a, s1a, h1a, w1b, b1b, s1b,
                                    h1b, w1c, b1c, s1c, h1c, xh, xl, sq, xb);
  k_knn2<<<1024, 256, 0, stream>>>(xh, xl, sq, idx);
  k_pq<<<4096, 256, 0, stream>>>(xh, xl, w2, Pb, Qb);
  k_prep<<<96, 256, 0, stream>>>(wl, wlb);  // after k_pq: xh/xl dead
  k_gmax<<<32768, 256, 0, stream>>>(Pb, Qb, idx, b2, s2, h2, xb);
  k_linl_mfma<<<4096, 256, 0, stream>>>(xb, wlb, pool_part);
  k_head<<<32, 256, 0, stream>>>(pool_part, bl, sl, hl, wm1, bm1, sm1, hm1, wm2,
                                 bm2, sm2, hm2, wout, bout, out);
}

// Round 6
// 683.425 us; speedup vs baseline: 2.6126x; 1.0939x over previous
//
#include <hip/hip_runtime.h>

#define DEV __device__ __forceinline__
DEV float relu_(float x) { return fmaxf(x, 0.0f); }

typedef __attribute__((ext_vector_type(4))) float f32x4;
typedef __attribute__((ext_vector_type(8))) __bf16 bf16x8;

DEV void knn_insert(float (&bd)[5], int (&bi)[5], float d, int j) {
  if (d >= bd[4]) return;
  bd[4] = d; bi[4] = j;
#pragma unroll
  for (int p = 4; p > 0; --p) {
    if (bd[p] < bd[p - 1]) {
      float td = bd[p]; bd[p] = bd[p - 1]; bd[p - 1] = td;
      int ti = bi[p]; bi[p] = bi[p - 1]; bi[p - 1] = ti;
    }
  }
}

// ---------------- Kernel 1: kNN on pos (F=3), 4-way candidate split ----------------
__global__ __launch_bounds__(256) void k_knn1(const float* __restrict__ pos,
                                              int* __restrict__ idx1) {
  __shared__ float ps[6144];
  __shared__ float sqs[2048];
  __shared__ float md[640];
  __shared__ int mi[640];
  int tid = threadIdx.x;
  int b = blockIdx.x >> 5, qc = blockIdx.x & 31;
  const float* src = pos + b * 6144;
  for (int u = tid; u < 6144; u += 256) ps[u] = src[u];
  __syncthreads();
  for (int u = tid; u < 2048; u += 256) {
    float x = ps[u * 3], y = ps[u * 3 + 1], z = ps[u * 3 + 2];
    sqs[u] = fmaf(z, z, fmaf(y, y, x * x));
  }
  __syncthreads();
  int q = tid & 63, sub = tid >> 6;
  int qi = qc * 64 + q;
  float qx = ps[qi * 3], qy = ps[qi * 3 + 1], qz = ps[qi * 3 + 2];
  float qsq = sqs[qi];
  float bd[5] = {1e30f, 1e30f, 1e30f, 1e30f, 1e30f};
  int bi[5] = {0, 0, 0, 0, 0};
  int j0 = sub * 512;
  for (int j = j0; j < j0 + 512; ++j) {
    float px = ps[j * 3], py = ps[j * 3 + 1], pz = ps[j * 3 + 2];
    float dot = fmaf(qz, pz, fmaf(qy, py, qx * px));
    float d = (qsq + sqs[j]) - 2.0f * dot;
    knn_insert(bd, bi, d, j);
  }
  for (int half = 2; half >= 1; half >>= 1) {
    __syncthreads();
    if (sub >= half && sub < 2 * half) {
      int slot = (q * 2 + (sub - half)) * 5;
#pragma unroll
      for (int k = 0; k < 5; ++k) { md[slot + k] = bd[k]; mi[slot + k] = bi[k]; }
    }
    __syncthreads();
    if (sub < half) {
      int slot = (q * 2 + sub) * 5;
#pragma unroll
      for (int k = 0; k < 5; ++k) knn_insert(bd, bi, md[slot + k], mi[slot + k]);
    }
  }
  if (sub == 0) {
    int* op = idx1 + (b * 2048 + qi) * 5;
#pragma unroll
    for (int k = 0; k < 5; ++k) op[k] = bi[k];
  }
}

// ---------------- Kernel 1b: per-point u/v for EdgeConv1 layer-1 ----------------
// u_i = xi@(Wtop-Wbot)+b1a (transposed [b][f][n]); v_j = xj@Wbot (row-major [n][64])
__global__ __launch_bounds__(256) void k_uv(const float* __restrict__ pos,
                                            const float* __restrict__ w1a,
                                            const float* __restrict__ b1a,
                                            float* __restrict__ ut,
                                            float* __restrict__ v) {
  __shared__ float wAs[384];
  __shared__ float bs[64];
  int tid = threadIdx.x;
  for (int u = tid; u < 384; u += 256) wAs[u] = w1a[u];  // FIX: strided (384 > 256)
  if (tid < 64) bs[tid] = b1a[tid];
  __syncthreads();
  int lane = tid & 63, fq = tid >> 6;
  int p = blockIdx.x * 64 + lane;
  int b = p >> 11, nloc = p & 2047;
  float x0 = pos[p * 3], x1 = pos[p * 3 + 1], x2 = pos[p * 3 + 2];
  float uu[16], vv[16];
#pragma unroll
  for (int m = 0; m < 16; ++m) {
    int f = fq * 16 + m;
    float wt0 = wAs[f], wt1 = wAs[64 + f], wt2 = wAs[128 + f];
    float wb0 = wAs[192 + f], wb1 = wAs[256 + f], wb2 = wAs[320 + f];
    float uval = bs[f];
    uval = fmaf(x0, wt0 - wb0, uval);
    uval = fmaf(x1, wt1 - wb1, uval);
    uval = fmaf(x2, wt2 - wb2, uval);
    uu[m] = uval;
    vv[m] = fmaf(x2, wb2, fmaf(x1, wb1, x0 * wb0));
  }
#pragma unroll
  for (int m = 0; m < 16; ++m)
    ut[((size_t)b * 64 + fq * 16 + m) * 2048 + nloc] = uu[m];
#pragma unroll
  for (int it = 0; it < 4; ++it)
    *(float4*)(v + (size_t)p * 64 + fq * 16 + it * 4) = *(const float4*)(vv + it * 4);
}

// ---------------- Kernel 2: EdgeConv1 layers 2/3 as 4x4-blocked GEMM ----------------
// grid 1024 (64 points/block), block 256. Outputs xh/xl bf16, sq fp32, xb[0:64].
__global__ __launch_bounds__(256) void k_edge1(
    const int* __restrict__ idx1, const float* __restrict__ ut,
    const float* __restrict__ v,
    const float* __restrict__ s1a, const float* __restrict__ h1a,
    const float* __restrict__ w1b, const float* __restrict__ b1b,
    const float* __restrict__ s1b, const float* __restrict__ h1b,
    const float* __restrict__ w1c, const float* __restrict__ b1c,
    const float* __restrict__ s1c, const float* __restrict__ h1c,
    __bf16* __restrict__ xh, __bf16* __restrict__ xl,
    float* __restrict__ sqo, __bf16* __restrict__ xb) {
  __shared__ __align__(16) float h1t[64 * 68];  // [f][e] stride 68
  __shared__ __align__(16) float h2t[64 * 68];
  __shared__ __align__(16) float wB[4096], wC[4096];
  __shared__ float cA[128], cB[192], cC[192];
  __shared__ float red[64 * 17];
  int tid = threadIdx.x;
  for (int u = tid; u < 4096; u += 256) { wB[u] = w1b[u]; wC[u] = w1c[u]; }
  if (tid < 64) {
    cA[tid] = s1a[tid]; cA[64 + tid] = h1a[tid];
    cB[tid] = b1b[tid]; cB[64 + tid] = s1b[tid]; cB[128 + tid] = h1b[tid];
    cC[tid] = b1c[tid]; cC[64 + tid] = s1c[tid]; cC[128 + tid] = h1c[tid];
  }
  int p0 = blockIdx.x * 64;
  int b = p0 >> 11, nloc0 = p0 & 2047;
  size_t bb = (size_t)b * 2048;
  int e = tid & 63, fq = tid >> 6;         // h1-build mapping
  int cg = tid >> 4, pg = tid & 15;        // GEMM mapping
  float amax[4][4];
#pragma unroll
  for (int i = 0; i < 4; ++i)
#pragma unroll
    for (int j = 0; j < 4; ++j) amax[i][j] = -3.4e38f;
  __syncthreads();
  for (int k = 0; k < 5; ++k) {
    // ---- build h1t[f][e] = relu(u_i + v_j)*s1a+h1a ----
    {
      int j = idx1[(p0 + e) * 5 + k];
      const float* vrow = v + (bb + j) * 64 + fq * 16;
#pragma unroll
      for (int it = 0; it < 4; ++it) {
        float4 vv = *(const float4*)(vrow + it * 4);
        float vr[4] = {vv.x, vv.y, vv.z, vv.w};
#pragma unroll
        for (int m = 0; m < 4; ++m) {
          int f = fq * 16 + it * 4 + m;
          float uval = ut[((size_t)b * 64 + f) * 2048 + nloc0 + e];
          h1t[f * 68 + e] = relu_(uval + vr[m]) * cA[f] + cA[64 + f];
        }
      }
    }
    __syncthreads();
    // ---- layer2: h2 = act(h1 @ W1b) ----
    {
      float acc[4][4] = {{0, 0, 0, 0}, {0, 0, 0, 0}, {0, 0, 0, 0}, {0, 0, 0, 0}};
#pragma unroll 4
      for (int f = 0; f < 64; ++f) {
        float4 av = *(const float4*)(h1t + f * 68 + pg * 4);
        float4 wv = *(const float4*)(wB + f * 64 + cg * 4);
        float a[4] = {av.x, av.y, av.z, av.w};
        float w[4] = {wv.x, wv.y, wv.z, wv.w};
#pragma unroll
        for (int ii = 0; ii < 4; ++ii)
#pragma unroll
          for (int jj = 0; jj < 4; ++jj)
            acc[ii][jj] = fmaf(a[ii], w[jj], acc[ii][jj]);
      }
#pragma unroll
      for (int jj = 0; jj < 4; ++jj) {
        int c = cg * 4 + jj;
        float bv = cB[c], sv = cB[64 + c], hv = cB[128 + c];
#pragma unroll
        for (int ii = 0; ii < 4; ++ii)
          h2t[c * 68 + pg * 4 + ii] = relu_(acc[ii][jj] + bv) * sv + hv;
      }
    }
    __syncthreads();
    // ---- layer3: pre-act accumulate + max over k ----
    {
      float acc[4][4] = {{0, 0, 0, 0}, {0, 0, 0, 0}, {0, 0, 0, 0}, {0, 0, 0, 0}};
#pragma unroll 4
      for (int f = 0; f < 64; ++f) {
        float4 av = *(const float4*)(h2t + f * 68 + pg * 4);
        float4 wv = *(const float4*)(wC + f * 64 + cg * 4);
        float a[4] = {av.x, av.y, av.z, av.w};
        float w[4] = {wv.x, wv.y, wv.z, wv.w};
#pragma unroll
        for (int ii = 0; ii < 4; ++ii)
#pragma unroll
          for (int jj = 0; jj < 4; ++jj)
            acc[ii][jj] = fmaf(a[ii], w[jj], acc[ii][jj]);
      }
#pragma unroll
      for (int ii = 0; ii < 4; ++ii)
#pragma unroll
        for (int jj = 0; jj < 4; ++jj)
          amax[ii][jj] = fmaxf(amax[ii][jj], acc[ii][jj]);
    }
    __syncthreads();
  }
  // ---- epilogue: activation (monotone), bf16 hi/lo split, sq ----
#pragma unroll
  for (int ii = 0; ii < 4; ++ii) {
    int n = p0 + pg * 4 + ii;
    float sqp = 0.f;
    __bf16 oh[4], ol[4], ob[4];
#pragma unroll
    for (int jj = 0; jj < 4; ++jj) {
      int c = cg * 4 + jj;
      float val = relu_(amax[ii][jj] + cC[c]) * cC[64 + c] + cC[128 + c];
      sqp = fmaf(val, val, sqp);
      __bf16 h = (__bf16)val;
      oh[jj] = h;
      ol[jj] = (__bf16)(val - (float)h);
      ob[jj] = h;
    }
    *(uint2*)(xh + (size_t)n * 64 + cg * 4) = *(const uint2*)oh;
    *(uint2*)(xl + (size_t)n * 64 + cg * 4) = *(const uint2*)ol;
    *(uint2*)(xb + (size_t)n * 192 + cg * 4) = *(const uint2*)ob;
    red[(pg * 4 + ii) * 17 + cg] = sqp;
  }
  __syncthreads();
  if (tid < 64) {
    float s = 0.f;
#pragma unroll
    for (int g = 0; g < 16; ++g) s += red[tid * 17 + g];
    sqo[p0 + tid] = s;
  }
}

// ---------------- Kernel 3: kNN on x1 via MFMA hi/lo split ----------------
__global__ __launch_bounds__(256) void k_knn2(const __bf16* __restrict__ xh,
                                              const __bf16* __restrict__ xl,
                                              const float* __restrict__ sq,
                                              int* __restrict__ idx2) {
  __shared__ __align__(16) __bf16 Bh[64 * 72];
  __shared__ __align__(16) __bf16 Bl[64 * 72];
  __shared__ float sqs[2048];
  int tid = threadIdx.x;
  int w = tid >> 6, lane = tid & 63;
  int quad = lane >> 4, lm = lane & 15;
  int b = blockIdx.x >> 5, qc = blockIdx.x & 31;
  int q0 = qc * 64;
  size_t bb = (size_t)b * 2048;
  for (int u = tid; u < 512; u += 256)
    *(float4*)(sqs + u * 4) = *(const float4*)(sq + bb + u * 4);
  const __bf16* qh = xh + (bb + q0 + w * 16 + lm) * 64 + quad * 8;
  const __bf16* ql = xl + (bb + q0 + w * 16 + lm) * 64 + quad * 8;
  bf16x8 Ah0 = *(const bf16x8*)(qh);
  bf16x8 Ah1 = *(const bf16x8*)(qh + 32);
  bf16x8 Al0 = *(const bf16x8*)(ql);
  bf16x8 Al1 = *(const bf16x8*)(ql + 32);
  __syncthreads();
  float qsq[4];
#pragma unroll
  for (int r = 0; r < 4; ++r) qsq[r] = sqs[q0 + w * 16 + quad * 4 + r];
  float bd[4][5];
  int bi[4][5];
#pragma unroll
  for (int r = 0; r < 4; ++r)
#pragma unroll
    for (int k = 0; k < 5; ++k) { bd[r][k] = 1e30f; bi[r][k] = 0; }
  for (int ct = 0; ct < 32; ++ct) {
#pragma unroll
    for (int pass = 0; pass < 2; ++pass) {
      int unit = pass * 256 + tid;
      int n = unit >> 3, cc = unit & 7;
      const __bf16* gsrc = xh + (bb + ct * 64 + n) * 64 + cc * 8;
      const __bf16* gsrl = xl + (bb + ct * 64 + n) * 64 + cc * 8;
      *(uint4*)(Bh + n * 72 + cc * 8) = *(const uint4*)gsrc;
      *(uint4*)(Bl + n * 72 + cc * 8) = *(const uint4*)gsrl;
    }
    __syncthreads();
#pragma unroll
    for (int nt = 0; nt < 4; ++nt) {
      const __bf16* bph = Bh + (nt * 16 + lm) * 72 + quad * 8;
      const __bf16* bpl = Bl + (nt * 16 + lm) * 72 + quad * 8;
      bf16x8 Bh0 = *(const bf16x8*)(bph);
      bf16x8 Bh1 = *(const bf16x8*)(bph + 32);
      bf16x8 Bl0 = *(const bf16x8*)(bpl);
      bf16x8 Bl1 = *(const bf16x8*)(bpl + 32);
      f32x4 acc = {0.f, 0.f, 0.f, 0.f};
      acc = __builtin_amdgcn_mfma_f32_16x16x32_bf16(Ah0, Bh0, acc, 0, 0, 0);
      acc = __builtin_amdgcn_mfma_f32_16x16x32_bf16(Ah1, Bh1, acc, 0, 0, 0);
      acc = __builtin_amdgcn_mfma_f32_16x16x32_bf16(Ah0, Bl0, acc, 0, 0, 0);
      acc = __builtin_amdgcn_mfma_f32_16x16x32_bf16(Ah1, Bl1, acc, 0, 0, 0);
      acc = __builtin_amdgcn_mfma_f32_16x16x32_bf16(Al0, Bh0, acc, 0, 0, 0);
      acc = __builtin_amdgcn_mfma_f32_16x16x32_bf16(Al1, Bh1, acc, 0, 0, 0);
      int cid = ct * 64 + nt * 16 + lm;
      float csq = sqs[cid];
#pragma unroll
      for (int r = 0; r < 4; ++r) {
        float d = (qsq[r] + csq) - 2.0f * acc[r];
        knn_insert(bd[r], bi[r], d, cid);
      }
    }
    __syncthreads();
  }
  for (int m = 1; m <= 8; m <<= 1) {
#pragma unroll
    for (int r = 0; r < 4; ++r) {
      float od[5]; int oi[5];
#pragma unroll
      for (int k = 0; k < 5; ++k) {
        od[k] = __shfl_xor(bd[r][k], m);
        oi[k] = __shfl_xor(bi[r][k], m);
      }
#pragma unroll
      for (int k = 0; k < 5; ++k) knn_insert(bd[r], bi[r], od[k], oi[k]);
    }
  }
  if (lm == 0) {
#pragma unroll
    for (int r = 0; r < 4; ++r) {
      int qi = q0 + w * 16 + quad * 4 + r;
      int* op = idx2 + (bb + qi) * 5;
#pragma unroll
      for (int k = 0; k < 5; ++k) op[k] = bi[r][k];
    }
  }
}

// ---------------- Kernel 4a: P = x1@(W1-W2), Q = x1@W2 (x1 = hi+lo) ----------------
__global__ __launch_bounds__(256) void k_pq(const __bf16* __restrict__ xh,
                                            const __bf16* __restrict__ xl,
                                            const float* __restrict__ w2,
                                            __bf16* __restrict__ Pb,
                                            __bf16* __restrict__ Qb) {
  __shared__ __align__(16) float ins[4096];
  int tid = threadIdx.x;
  int pt = blockIdx.x >> 2, oc = blockIdx.x & 3;
  int n0 = pt * 64;
#pragma unroll
  for (int pass = 0; pass < 2; ++pass) {
    int unit = pass * 256 + tid;
    int n = unit >> 3, cc = unit & 7;
    bf16x8 h = *(const bf16x8*)(xh + ((size_t)(n0 + n)) * 64 + cc * 8);
    bf16x8 l = *(const bf16x8*)(xl + ((size_t)(n0 + n)) * 64 + cc * 8);
#pragma unroll
    for (int j = 0; j < 8; ++j)
      ins[(cc * 8 + j) * 64 + n] = (float)h[j] + (float)l[j];
  }
  __syncthreads();
  int cg = tid >> 4, pg = tid & 15;
  int vcol = oc * 64 + cg * 4;
  bool isP = (oc < 2);
  int col = isP ? vcol : (vcol - 128);
  float acc[4][4] = {{0, 0, 0, 0}, {0, 0, 0, 0}, {0, 0, 0, 0}, {0, 0, 0, 0}};
#pragma unroll 4
  for (int k = 0; k < 64; ++k) {
    float4 av = *(const float4*)(ins + k * 64 + pg * 4);
    float a[4] = {av.x, av.y, av.z, av.w};
    float4 wBv = *(const float4*)(w2 + (64 + k) * 128 + col);
    float wv[4];
    if (isP) {
      float4 wAv = *(const float4*)(w2 + k * 128 + col);
      wv[0] = wAv.x - wBv.x; wv[1] = wAv.y - wBv.y;
      wv[2] = wAv.z - wBv.z; wv[3] = wAv.w - wBv.w;
    } else {
      wv[0] = wBv.x; wv[1] = wBv.y; wv[2] = wBv.z; wv[3] = wBv.w;
    }
#pragma unroll
    for (int ii = 0; ii < 4; ++ii)
#pragma unroll
      for (int jj = 0; jj < 4; ++jj)
        acc[ii][jj] = fmaf(a[ii], wv[jj], acc[ii][jj]);
  }
  __bf16* base = (isP ? Pb : Qb);
#pragma unroll
  for (int ii = 0; ii < 4; ++ii) {
    int n = n0 + pg * 4 + ii;
    __bf16 o[4];
#pragma unroll
    for (int jj = 0; jj < 4; ++jj) o[jj] = (__bf16)acc[ii][jj];
    *(uint2*)(base + (size_t)n * 128 + col) = *(const uint2*)o;
  }
}

// ---------------- Kernel 4p: repack wl -> MFMA-B frag order bf16 ----------------
__global__ __launch_bounds__(256) void k_prep(const float* __restrict__ wl,
                                              __bf16* __restrict__ wlb) {
  int t = blockIdx.x * 256 + threadIdx.x;
  int nt = t / 3072;
  int rem = t - nt * 3072;
  int ks = rem / 512;
  int rem2 = rem - ks * 512;
  int nb = rem2 >> 6, lane = rem2 & 63;
  int k0 = ks * 32 + (lane >> 4) * 8;
  int n = nt * 128 + nb * 16 + (lane & 15);
  __bf16 o[8];
#pragma unroll
  for (int j = 0; j < 8; ++j) o[j] = (__bf16)wl[(k0 + j) * 1024 + n];
  *(uint4*)(wlb + (size_t)t * 8) = *(const uint4*)o;
}

// ---------------- Kernel 4b: gather-max + activation -> xb bf16 [n][64:192] ----------------
__global__ __launch_bounds__(256) void k_gmax(const __bf16* __restrict__ Pb,
                                              const __bf16* __restrict__ Qb,
                                              const int* __restrict__ idx2,
                                              const float* __restrict__ b2,
                                              const float* __restrict__ s2,
                                              const float* __restrict__ h2v,
                                              __bf16* __restrict__ xb) {
  int tid = threadIdx.x;
  int c = tid & 127, p = tid >> 7;
  int n = blockIdx.x * 2 + p;
  int b = n >> 11;
  const int* ip = idx2 + n * 5;
  float m = -3.4e38f;
#pragma unroll
  for (int k = 0; k < 5; ++k) {
    int j = ip[k];
    m = fmaxf(m, (float)Qb[((size_t)(b * 2048 + j)) * 128 + c]);
  }
  float v = (float)Pb[(size_t)n * 128 + c] + m + b2[c];
  xb[(size_t)n * 192 + 64 + c] = (__bf16)(relu_(v) * s2[c] + h2v[c]);
}

// ---------------- Kernel 5: bf16 MFMA GEMM fused point-max ----------------
__global__ __launch_bounds__(256) void k_linl_mfma(const __bf16* __restrict__ xb,
                                                   const __bf16* __restrict__ wlb,
                                                   float* __restrict__ pool_part) {
  __shared__ __align__(16) __bf16 Al[4096];
  __shared__ __align__(16) __bf16 Bl[4096];
  __shared__ float red[256];
  int tid = threadIdx.x;
  int w = tid >> 6, lane = tid & 63;
  int mt = blockIdx.x >> 3, nt = blockIdx.x & 7;
  int n0 = mt << 7;
  int wm = w & 1, wn = w >> 1;
  int quad = lane >> 4, lm = lane & 15;
  f32x4 acc[4][4];
#pragma unroll
  for (int i = 0; i < 4; ++i)
#pragma unroll
    for (int j = 0; j < 4; ++j) acc[i][j] = (f32x4){0.f, 0.f, 0.f, 0.f};
  for (int ks = 0; ks < 6; ++ks) {
    __syncthreads();
#pragma unroll
    for (int u = 0; u < 2; ++u) {
      int mb = w * 2 + u;
      const uint4* ga = (const uint4*)(xb + (size_t)(n0 + mb * 16 + lm) * 192 + ks * 32 + quad * 8);
      *(uint4*)(Al + (mb * 64 + lane) * 8) = *ga;
      const uint4* gb = (const uint4*)(wlb + ((((size_t)nt * 6 + ks) * 8 + mb) * 64 + lane) * 8);
      *(uint4*)(Bl + (mb * 64 + lane) * 8) = *gb;
    }
    __syncthreads();
    bf16x8 af[4], bfr[4];
#pragma unroll
    for (int i = 0; i < 4; ++i) {
      af[i] = *(const bf16x8*)(Al + ((wm * 4 + i) * 64 + lane) * 8);
      bfr[i] = *(const bf16x8*)(Bl + ((wn * 4 + i) * 64 + lane) * 8);
    }
#pragma unroll
    for (int i = 0; i < 4; ++i)
#pragma unroll
      for (int j = 0; j < 4; ++j)
        acc[i][j] = __builtin_amdgcn_mfma_f32_16x16x32_bf16(af[i], bfr[j], acc[i][j], 0, 0, 0);
  }
  float pm[4];
#pragma unroll
  for (int j = 0; j < 4; ++j) {
    float m = -3.4e38f;
#pragma unroll
    for (int i = 0; i < 4; ++i)
#pragma unroll
      for (int r = 0; r < 4; ++r) m = fmaxf(m, acc[i][j][r]);
    m = fmaxf(m, __shfl_xor(m, 16));
    m = fmaxf(m, __shfl_xor(m, 32));
    pm[j] = m;
  }
  __syncthreads();
  if (quad == 0) {
#pragma unroll
    for (int j = 0; j < 4; ++j) red[w * 64 + j * 16 + lm] = pm[j];
  }
  __syncthreads();
  if (tid < 128) {
    int wn2 = tid >> 6, cc = tid & 63;
    float v = fmaxf(red[(wn2 * 2) * 64 + cc], red[(wn2 * 2 + 1) * 64 + cc]);
    pool_part[(size_t)mt * 1024 + nt * 128 + wn2 * 64 + cc] = v;
  }
}

// ---------------- Kernel 6: head MLP ----------------
__global__ __launch_bounds__(256) void k_head(
    const float* __restrict__ pool_part, const float* __restrict__ bl,
    const float* __restrict__ sl, const float* __restrict__ hl,
    const float* __restrict__ wm1, const float* __restrict__ bm1,
    const float* __restrict__ sm1, const float* __restrict__ hm1,
    const float* __restrict__ wm2, const float* __restrict__ bm2,
    const float* __restrict__ sm2, const float* __restrict__ hm2,
    const float* __restrict__ wout, const float* __restrict__ bout,
    float* __restrict__ out) {
  __shared__ float p_s[1024], h1_s[512], h2_s[256];
  int b = blockIdx.x, tid = threadIdx.x;
  for (int c = tid; c < 1024; c += 256) {
    float m = -3.4e38f;
#pragma unroll 4
    for (int t = 0; t < 16; ++t)
      m = fmaxf(m, pool_part[(size_t)(b * 16 + t) * 1024 + c]);
    p_s[c] = relu_(m + bl[c]) * sl[c] + hl[c];
  }
  __syncthreads();
  for (int c = tid; c < 512; c += 256) {
    float a0 = 0, a1 = 0, a2 = 0, a3 = 0;
    for (int f = 0; f < 1024; f += 4) {
      a0 = fmaf(p_s[f], wm1[f * 512 + c], a0);
      a1 = fmaf(p_s[f + 1], wm1[(f + 1) * 512 + c], a1);
      a2 = fmaf(p_s[f + 2], wm1[(f + 2) * 512 + c], a2);
      a3 = fmaf(p_s[f + 3], wm1[(f + 3) * 512 + c], a3);
    }
    float a = (a0 + a1) + (a2 + a3);
    h1_s[c] = relu_(a + bm1[c]) * sm1[c] + hm1[c];
  }
  __syncthreads();
  if (tid < 256) {
    float a0 = 0, a1 = 0, a2 = 0, a3 = 0;
    for (int f = 0; f < 512; f += 4) {
      a0 = fmaf(h1_s[f], wm2[f * 256 + tid], a0);
      a1 = fmaf(h1_s[f + 1], wm2[(f + 1) * 256 + tid], a1);
      a2 = fmaf(h1_s[f + 2], wm2[(f + 2) * 256 + tid], a2);
      a3 = fmaf(h1_s[f + 3], wm2[(f + 3) * 256 + tid], a3);
    }
    float a = (a0 + a1) + (a2 + a3);
    h2_s[tid] = relu_(a + bm2[tid]) * sm2[tid] + hm2[tid];
  }
  __syncthreads();
  if (tid < 2) {
    float a0 = 0, a1 = 0;
    for (int f = 0; f < 256; f += 2) {
      a0 = fmaf(h2_s[f], wout[f * 2 + tid], a0);
      a1 = fmaf(h2_s[f + 1], wout[(f + 1) * 2 + tid], a1);
    }
    out[b * 2 + tid] = (a0 + a1) + bout[tid];
  }
}

extern "C" void kernel_launch(void* const* d_in, const int* in_sizes, int n_in,
                              void* d_out, int out_size, void* d_ws, size_t ws_size,
                              hipStream_t stream) {
  const float* pos = (const float*)d_in[0];
  const float* w1a = (const float*)d_in[1];
  const float* b1a = (const float*)d_in[2];
  const float* s1a = (const float*)d_in[3];
  const float* h1a = (const float*)d_in[4];
  const float* w1b = (const float*)d_in[5];
  const float* b1b = (const float*)d_in[6];
  const float* s1b = (const float*)d_in[7];
  const float* h1b = (const float*)d_in[8];
  const float* w1c = (const float*)d_in[9];
  const float* b1c = (const float*)d_in[10];
  const float* s1c = (const float*)d_in[11];
  const float* h1c = (const float*)d_in[12];
  const float* w2 = (const float*)d_in[13];
  const float* b2 = (const float*)d_in[14];
  const float* s2 = (const float*)d_in[15];
  const float* h2 = (const float*)d_in[16];
  const float* wl = (const float*)d_in[17];
  const float* bl = (const float*)d_in[18];
  const float* sl = (const float*)d_in[19];
  const float* hl = (const float*)d_in[20];
  const float* wm1 = (const float*)d_in[21];
  const float* bm1 = (const float*)d_in[22];
  const float* sm1 = (const float*)d_in[23];
  const float* hm1 = (const float*)d_in[24];
  const float* wm2 = (const float*)d_in[25];
  const float* bm2 = (const float*)d_in[26];
  const float* sm2 = (const float*)d_in[27];
  const float* hm2 = (const float*)d_in[28];
  const float* wout = (const float*)d_in[29];
  const float* bout = (const float*)d_in[30];
  float* out = (float*)d_out;

  // workspace (float units): xh | xl | Pb | Qb | xb | idx | sq   (~74 MB)
  float* base = (float*)d_ws;
  __bf16* xh = (__bf16*)base;                   // 4,194,304 bf16
  __bf16* xl = (__bf16*)(base + 2097152);       // 4,194,304 bf16
  float* PbF = base + 4194304;                  // 4,194,304 f
  float* QbF = PbF + 4194304;                   // 4,194,304 f
  float* xbF = QbF + 4194304;                   // 6,291,456 f
  int* idx = (int*)(xbF + 6291456);             // 327,680 ints
  float* sq = (float*)(idx + 327680);           // 65,536 f
  __bf16* Pb = (__bf16*)PbF;
  __bf16* Qb = (__bf16*)QbF;
  __bf16* xb = (__bf16*)xbF;
  // u/v alias Pb/Qb regions (dead until k_pq; u/v dead after k_edge1)
  float* ut = PbF;                              // [b][64][2048] fp32 = 16 MB
  float* vv = QbF;                              // [n][64] fp32 = 16 MB
  // wlb/pool_part alias xh/xl region (dead after k_pq)
  __bf16* wlb = (__bf16*)base;
  float* pool_part = base + 131072;

  k_knn1<<<1024, 256, 0, stream>>>(pos, idx);
  k_uv<<<1024, 256, 0, stream>>>(pos, w1a, b1a, ut, vv);
  k_edge1<<<1024, 256, 0, stream>>>(idx, ut, vv, s1a, h1a, w1b, b1b, s1b, h1b,
                                    w1c, b1c, s1c, h1c, xh, xl, sq, xb);
  k_knn2<<<1024, 256, 0, stream>>>(xh, xl, sq, idx);
  k_pq<<<4096, 256, 0, stream>>>(xh, xl, w2, Pb, Qb);
  k_prep<<<96, 256, 0, stream>>>(wl, wlb);
  k_gmax<<<32768, 256, 0, stream>>>(Pb, Qb, idx, b2, s2, h2, xb);
  k_linl_mfma<<<4096, 256, 0, stream>>>(xb, wlb, pool_part);
  k_head<<<32, 256, 0, stream>>>(pool_part, bl, sl, hl, wm1, bm1, sm1, hm1, wm2,
                                 bm2, sm2, hm2, wout, bout, out);
}